// Round 15
// baseline (1866.673 us; speedup 1.0000x reference)
//
#include <hip/hip_runtime.h>
#include <hip/hip_bf16.h>
#include <math.h>

// ---------------- constants ----------------
static constexpr int E   = 768;
static constexpr int NH  = 12;
static constexpr int HD  = 64;
static constexpr int Bsz = 2;
static constexpr int G   = 32;
static constexpr int NTOK = G * G;      // 1024
static constexpr int ROWS = Bsz * NTOK; // 2048
static constexpr int WS  = 14;
static constexpr int NWIN_SIDE = 3;
static constexpr int NWIN = NWIN_SIDE * NWIN_SIDE;
static constexpr int BW  = Bsz * NWIN;   // 18
static constexpr int NW  = WS * WS;      // 196
static constexpr int WROWS = BW * NW;    // 3528
static constexpr int WIN_MASK = 0x6DB;

typedef __attribute__((ext_vector_type(8))) short short8;
typedef __attribute__((ext_vector_type(4))) float f32x4;
typedef unsigned short ushort_t;

__device__ __forceinline__ unsigned short f2bf(float x) {
  union { float f; unsigned u; } v; v.f = x;
  unsigned r = v.u + 0x7fffu + ((v.u >> 16) & 1u);
  return (unsigned short)(r >> 16);
}
__device__ __forceinline__ float bf2f(unsigned short h) {
  union { unsigned u; float f; } v; v.u = ((unsigned)h) << 16;
  return v.f;
}

__device__ __forceinline__ void glds16(const void* g, void* l) {
  __builtin_amdgcn_global_load_lds(
      (const __attribute__((address_space(1))) unsigned*)g,
      (__attribute__((address_space(3))) unsigned*)l, 16, 0, 0);
}

// ---------------- LayerNorm fp32 -> bf16, one wave per row ----------------
__global__ __launch_bounds__(256) void ln_kernel(
    const float* __restrict__ in, const float* __restrict__ w,
    const float* __restrict__ b, ushort_t* __restrict__ out) {
  const int wave = threadIdx.x >> 6, lane = threadIdx.x & 63;
  const int row = blockIdx.x * 4 + wave;
  const float4* r4 = (const float4*)(in + (size_t)row * E);
  float4 v[3];
  v[0] = r4[lane]; v[1] = r4[lane + 64]; v[2] = r4[lane + 128];
  float s = 0.f, s2 = 0.f;
#pragma unroll
  for (int i = 0; i < 3; i++) {
    s += v[i].x + v[i].y + v[i].z + v[i].w;
    s2 += v[i].x * v[i].x + v[i].y * v[i].y + v[i].z * v[i].z + v[i].w * v[i].w;
  }
#pragma unroll
  for (int off = 1; off <= 32; off <<= 1) {
    s += __shfl_xor(s, off);
    s2 += __shfl_xor(s2, off);
  }
  const float mean = s * (1.f / E);
  const float var  = s2 * (1.f / E) - mean * mean;
  const float rs   = rsqrtf(var + 1e-6f);
  ushort_t* o = out + (size_t)row * E;
#pragma unroll
  for (int i = 0; i < 3; i++) {
    const int e0 = (lane + i * 64) * 4;
    ushort4 p;
    p.x = f2bf((v[i].x - mean) * rs * w[e0]     + b[e0]);
    p.y = f2bf((v[i].y - mean) * rs * w[e0 + 1] + b[e0 + 1]);
    p.z = f2bf((v[i].z - mean) * rs * w[e0 + 2] + b[e0 + 2]);
    p.w = f2bf((v[i].w - mean) * rs * w[e0 + 3] + b[e0 + 3]);
    *(ushort4*)&o[e0] = p;
  }
}

enum { OP_QKV = 0, OP_GELU = 1, OP_ADD = 2, OP_POS = 3, OP_HEAD = 4 };

// ---------------- bf16 GEMM, 64x64 tile, 4 waves, counted-vmcnt 2-phase ----
template <int OP, int MAP>
__global__ __launch_bounds__(256) void gemm_bt(
    const ushort_t* __restrict__ A, const ushort_t* __restrict__ Bt,
    const float* __restrict__ bias, const float* __restrict__ res,
    const float* __restrict__ pos, void* __restrict__ Cp,
    int M, int N, int K, int ncol) {
  __shared__ ushort_t As[2][64 * 64];
  __shared__ ushort_t Bs[2][64 * 64];
  const int tid = threadIdx.x, wave = tid >> 6, lane = tid & 63;
  const int lx = lane & 15, ly = lane >> 4;

  const int nwg = gridDim.x;
  const int q = nwg >> 3, r = nwg & 7;
  const int xcd = blockIdx.x & 7, loc = blockIdx.x >> 3;
  const int wgid = ((xcd < r) ? xcd * (q + 1) : r * (q + 1) + (xcd - r) * q) + loc;
  const int brow = wgid / ncol, bcol = wgid - brow * ncol;
  const int row0 = brow * 64, col0 = bcol * 64;
  const int wm = (wave >> 1) * 32, wn = (wave & 1) * 32;
  const int rin = lane >> 3, pseg = lane & 7;
  const int lseg = pseg ^ rin;
  f32x4 acc[2][2] = {};

  const ushort_t* aptr[2];
  const ushort_t* bptr[2];
#pragma unroll
  for (int j = 0; j < 2; j++) {
    const int slot = wave * 2 + j;
    int ar = row0 + slot * 8 + rin;
    if (ar >= M) ar = M - 1;
    if (MAP == 2) {
      const int bI = ar >> 10, t = ar & 1023, y = t >> 5, x = t & 31;
      const int by = y / WS, wy = y - by * WS;
      const int bx = x / WS, wx = x - bx * WS;
      const int win = bI * NWIN + by * NWIN_SIDE + bx;
      aptr[j] = &A[((size_t)win * NW + wy * WS + wx) * E + lseg * 8];
    } else {
      aptr[j] = &A[(size_t)ar * K + lseg * 8];
    }
    const int br = col0 + slot * 8 + rin;
    bptr[j] = &Bt[(size_t)br * K + lseg * 8];
  }

#pragma unroll
  for (int j = 0; j < 2; j++) {
    const int slot = wave * 2 + j;
    glds16(aptr[j], &As[0][slot * 512]);
    glds16(bptr[j], &Bs[0][slot * 512]);
  }

  const int nt = K >> 6;
  for (int t = 0; t < nt; t++) {
    const int cur = t & 1;
    if (t + 1 < nt) {
      const int k1 = (t + 1) << 6;
#pragma unroll
      for (int j = 0; j < 2; j++) {
        const int slot = wave * 2 + j;
        glds16(aptr[j] + k1, &As[cur ^ 1][slot * 512]);
        glds16(bptr[j] + k1, &Bs[cur ^ 1][slot * 512]);
      }
      asm volatile("s_waitcnt vmcnt(4)" ::: "memory");
    } else {
      asm volatile("s_waitcnt vmcnt(0)" ::: "memory");
    }
    __builtin_amdgcn_s_barrier();
    __builtin_amdgcn_sched_barrier(0);
#pragma unroll
    for (int kb = 0; kb < 2; kb++) {
      short8 af[2], bfm[2];
#pragma unroll
      for (int m = 0; m < 2; m++) {
        const int rr = wm + m * 16 + lx;
        af[m] = *(const short8*)&As[cur][rr * 64 + (((kb * 4 + ly) ^ (rr & 7)) * 8)];
      }
#pragma unroll
      for (int n = 0; n < 2; n++) {
        const int rr = wn + n * 16 + lx;
        bfm[n] = *(const short8*)&Bs[cur][rr * 64 + (((kb * 4 + ly) ^ (rr & 7)) * 8)];
      }
      __builtin_amdgcn_s_setprio(1);
#pragma unroll
      for (int m = 0; m < 2; m++)
#pragma unroll
        for (int n = 0; n < 2; n++)
          acc[m][n] = __builtin_amdgcn_mfma_f32_16x16x32_bf16(af[m], bfm[n], acc[m][n], 0, 0, 0);
      __builtin_amdgcn_s_setprio(0);
    }
    asm volatile("s_waitcnt lgkmcnt(0)" ::: "memory");
    __builtin_amdgcn_s_barrier();
    __builtin_amdgcn_sched_barrier(0);
  }

#pragma unroll
  for (int m = 0; m < 2; m++) {
#pragma unroll
    for (int r4 = 0; r4 < 4; r4++) {
      const int gr = row0 + wm + m * 16 + ly * 4 + r4;
      if (gr >= M) continue;
#pragma unroll
      for (int n = 0; n < 2; n++) {
        const int gc = col0 + wn + n * 16 + lx;
        float v = acc[m][n][r4] + bias[gc];
        if (OP == OP_GELU) v = 0.5f * v * (1.f + erff(v * 0.70710678118654752f));
        if (OP == OP_ADD)  v += res[(size_t)gr * N + gc];
        if (OP == OP_POS)  v += pos[(size_t)(gr & 1023) * N + gc];
        if (OP == OP_QKV || OP == OP_GELU)
          ((ushort_t*)Cp)[(size_t)gr * N + gc] = f2bf(v);
        else if (OP == OP_HEAD)
          ((float*)Cp)[(((size_t)(gr >> 10) * 256 + gc) << 10) | (gr & 1023)] = v;
        else
          ((float*)Cp)[(size_t)gr * N + gc] = v;
      }
    }
  }
}

// ---------------- bf16 GEMM, 32x64 tile, 2 waves, for small-N GEMMs --------
template <int OP, int MAP>
__global__ __launch_bounds__(128) void gemm_32(
    const ushort_t* __restrict__ A, const ushort_t* __restrict__ Bt,
    const float* __restrict__ bias, const float* __restrict__ res,
    const float* __restrict__ pos, void* __restrict__ Cp,
    int M, int N, int K, int ncol) {
  __shared__ ushort_t As[2][32 * 64];
  __shared__ ushort_t Bs[2][64 * 64];
  const int tid = threadIdx.x, wave = tid >> 6, lane = tid & 63;
  const int lx = lane & 15, ly = lane >> 4;

  const int nwg = gridDim.x;
  const int q = nwg >> 3, r = nwg & 7;
  const int xcd = blockIdx.x & 7, loc = blockIdx.x >> 3;
  const int wgid = ((xcd < r) ? xcd * (q + 1) : r * (q + 1) + (xcd - r) * q) + loc;
  const int brow = wgid / ncol, bcol = wgid - brow * ncol;
  const int row0 = brow * 32, col0 = bcol * 64;
  const int wn = wave * 32;
  const int rin = lane >> 3, pseg = lane & 7;
  const int lseg = pseg ^ rin;
  f32x4 acc[2][2] = {};

  const ushort_t* aptr[2];
  const ushort_t* bptr[4];
#pragma unroll
  for (int j = 0; j < 2; j++) {
    const int slot = wave * 2 + j;
    int ar = row0 + slot * 8 + rin;
    if (ar >= M) ar = M - 1;
    if (MAP == 2) {
      const int bI = ar >> 10, t = ar & 1023, y = t >> 5, x = t & 31;
      const int by = y / WS, wy = y - by * WS;
      const int bx = x / WS, wx = x - bx * WS;
      const int win = bI * NWIN + by * NWIN_SIDE + bx;
      aptr[j] = &A[((size_t)win * NW + wy * WS + wx) * E + lseg * 8];
    } else {
      aptr[j] = &A[(size_t)ar * K + lseg * 8];
    }
  }
#pragma unroll
  for (int j = 0; j < 4; j++) {
    const int slot = wave * 4 + j;
    const int br = col0 + slot * 8 + rin;
    bptr[j] = &Bt[(size_t)br * K + lseg * 8];
  }

#pragma unroll
  for (int j = 0; j < 2; j++) glds16(aptr[j], &As[0][(wave * 2 + j) * 512]);
#pragma unroll
  for (int j = 0; j < 4; j++) glds16(bptr[j], &Bs[0][(wave * 4 + j) * 512]);

  const int nt = K >> 6;
  for (int t = 0; t < nt; t++) {
    const int cur = t & 1;
    if (t + 1 < nt) {
      const int k1 = (t + 1) << 6;
#pragma unroll
      for (int j = 0; j < 2; j++) glds16(aptr[j] + k1, &As[cur ^ 1][(wave * 2 + j) * 512]);
#pragma unroll
      for (int j = 0; j < 4; j++) glds16(bptr[j] + k1, &Bs[cur ^ 1][(wave * 4 + j) * 512]);
      asm volatile("s_waitcnt vmcnt(6)" ::: "memory");
    } else {
      asm volatile("s_waitcnt vmcnt(0)" ::: "memory");
    }
    __builtin_amdgcn_s_barrier();
    __builtin_amdgcn_sched_barrier(0);
#pragma unroll
    for (int kb = 0; kb < 2; kb++) {
      short8 af[2], bfm[2];
#pragma unroll
      for (int m = 0; m < 2; m++) {
        const int rr = m * 16 + lx;
        af[m] = *(const short8*)&As[cur][rr * 64 + (((kb * 4 + ly) ^ (rr & 7)) * 8)];
      }
#pragma unroll
      for (int n = 0; n < 2; n++) {
        const int rr = wn + n * 16 + lx;
        bfm[n] = *(const short8*)&Bs[cur][rr * 64 + (((kb * 4 + ly) ^ (rr & 7)) * 8)];
      }
      __builtin_amdgcn_s_setprio(1);
#pragma unroll
      for (int m = 0; m < 2; m++)
#pragma unroll
        for (int n = 0; n < 2; n++)
          acc[m][n] = __builtin_amdgcn_mfma_f32_16x16x32_bf16(af[m], bfm[n], acc[m][n], 0, 0, 0);
      __builtin_amdgcn_s_setprio(0);
    }
    asm volatile("s_waitcnt lgkmcnt(0)" ::: "memory");
    __builtin_amdgcn_s_barrier();
    __builtin_amdgcn_sched_barrier(0);
  }

#pragma unroll
  for (int m = 0; m < 2; m++) {
#pragma unroll
    for (int r4 = 0; r4 < 4; r4++) {
      const int gr = row0 + m * 16 + ly * 4 + r4;
      if (gr >= M) continue;
#pragma unroll
      for (int n = 0; n < 2; n++) {
        const int gc = col0 + wn + n * 16 + lx;
        float v = acc[m][n][r4] + bias[gc];
        if (OP == OP_GELU) v = 0.5f * v * (1.f + erff(v * 0.70710678118654752f));
        if (OP == OP_ADD)  v += res[(size_t)gr * N + gc];
        if (OP == OP_POS)  v += pos[(size_t)(gr & 1023) * N + gc];
        if (OP == OP_QKV || OP == OP_GELU)
          ((ushort_t*)Cp)[(size_t)gr * N + gc] = f2bf(v);
        else if (OP == OP_HEAD)
          ((float*)Cp)[(((size_t)(gr >> 10) * 256 + gc) << 10) | (gr & 1023)] = v;
        else
          ((float*)Cp)[(size_t)gr * N + gc] = v;
      }
    }
  }
}

// ---------------- MFMA flash attention, 4 waves x 64 queries ----------------
template <int WIN>
__global__ __launch_bounds__(256) void attn64(
    const ushort_t* __restrict__ qkv, ushort_t* __restrict__ out,
    const float* __restrict__ relh, const float* __restrict__ relw,
    const float* __restrict__ qkvb, int Hd, int Wd) {
  const int Ntok = Hd * Wd;  // 196 or 1024
  __shared__ ushort_t smem[17664];
  ushort_t* Ks   = smem;           // main [0,2048): 32x64 swizzled
  ushort_t* Vst  = smem + 2048;    // main [2048,4608): [64][40]
  ushort_t* Qs   = smem;           // prologue [0,4096)
  ushort_t* RelS = smem;           // prologue phase 2 [0,4096)
  ushort_t* Ps   = smem + 4608;    // [4][16][40]
  ushort_t* Th   = smem + 7168;    // [64][66]
  ushort_t* Tw   = smem + 11392;   // [64][66]
  ushort_t* khw  = smem + 15616;   // [1024]
  ushort_t* ridx = smem + 16640;   // [1024]

  const int tid = threadIdx.x, wave = tid >> 6, lane = tid & 63;
  const int lx = lane & 15, ly = lane >> 4;
  const int bh = blockIdx.y;
  const int nh = bh % NH, wb = bh / NH;
  int by = 0, bx = 0, b_img;
  if (WIN) {
    b_img = wb / NWIN;
    const int wr = wb - b_img * NWIN;
    by = wr / NWIN_SIDE; bx = wr - by * NWIN_SIDE;
  } else {
    b_img = wb;
  }
  const int q0 = blockIdx.x * 64;
  const size_t base = (size_t)b_img * NTOK * 2304 + nh * 64;

  for (int k = tid; k < 1024; k += 256) {
    const int kc = min(k, Ntok - 1);
    const int kh = kc / Wd, kw = kc - kh * Wd;
    khw[k] = (ushort_t)((kh << 8) | kw);
    if (WIN) {
      const int gy = by * WS + kh, gx = bx * WS + kw;
      ridx[k] = (gy < G && gx < G) ? (ushort_t)(gy * G + gx) : (ushort_t)0xFFFF;
    }
  }
  __syncthreads();

#pragma unroll
  for (int i = 0; i < 2; i++) {
    const int fv = i * 256 + tid;
    const int row = fv >> 3, dv8 = (fv & 7) * 8;
    const int qq = min(q0 + row, Ntok - 1);
    int rI;
    if (WIN) {
      const int t = ridx[qq];
      rI = (t == 0xFFFF) ? 0 : t;
    } else {
      rI = qq;
    }
    short8 v = *(const short8*)&qkv[base + (size_t)rI * 2304 + dv8];
    *(short8*)&Qs[(row * 64 + dv8) ^ ((row & 7) << 3)] = v;
  }
  __syncthreads();

  short8 qa[2];
  {
    const int row = wave * 16 + lx;
#pragma unroll
    for (int kb = 0; kb < 2; kb++)
      qa[kb] = *(const short8*)&Qs[(row * 64 + kb * 32 + ly * 8) ^ ((row & 7) << 3)];
  }
  int qh_r[4], qw_r[4];
#pragma unroll
  for (int r = 0; r < 4; r++) {
    const int qc = min(q0 + wave * 16 + ly * 4 + r, Ntok - 1);
    qh_r[r] = qc / Wd;
    qw_r[r] = qc - qh_r[r] * Wd;
  }
  __syncthreads();

  for (int t = 0; t < 2; t++) {
    const float* rel = t ? relw : relh;
    const int TR = t ? (2 * Wd - 1) : (2 * Hd - 1);
#pragma unroll
    for (int i = 0; i < 2; i++) {
      const int fv = i * 256 + tid;
      const int row = fv >> 3, c8 = (fv & 7) * 8;
      short8 v = {};
      if (row < TR) {
        const float* rp = &rel[(size_t)row * 64 + c8];
        const float4 a = *(const float4*)rp;
        const float4 bq = *(const float4*)(rp + 4);
        v[0] = (short)f2bf(a.x);  v[1] = (short)f2bf(a.y);
        v[2] = (short)f2bf(a.z);  v[3] = (short)f2bf(a.w);
        v[4] = (short)f2bf(bq.x); v[5] = (short)f2bf(bq.y);
        v[6] = (short)f2bf(bq.z); v[7] = (short)f2bf(bq.w);
      }
      *(short8*)&RelS[(row * 64 + c8) ^ ((row & 7) << 3)] = v;
    }
    __syncthreads();
    const int NT = (TR + 15) >> 4;
    ushort_t* T = t ? Tw : Th;
    for (int nt = 0; nt < NT; nt++) {
      f32x4 a = {};
      __builtin_amdgcn_s_setprio(1);
#pragma unroll
      for (int kb = 0; kb < 2; kb++) {
        const int rrow = nt * 16 + lx;
        short8 bfv = *(const short8*)&RelS[(rrow * 64 + kb * 32 + ly * 8) ^ ((rrow & 7) << 3)];
        a = __builtin_amdgcn_mfma_f32_16x16x32_bf16(qa[kb], bfv, a, 0, 0, 0);
      }
      __builtin_amdgcn_s_setprio(0);
#pragma unroll
      for (int reg = 0; reg < 4; reg++)
        T[(wave * 16 + ly * 4 + reg) * 66 + nt * 16 + lx] = f2bf(a[reg]);
    }
    __syncthreads();
  }

  f32x4 o[4] = {};
  float m_[4], l_[4];
#pragma unroll
  for (int r = 0; r < 4; r++) { m_[r] = -3e38f; l_[r] = 0.f; }

  const int nkt = (Ntok + 31) >> 5;
  const int srow = tid >> 3, c7 = tid & 7, dv8s = c7 * 8;
  const int vswz = (c7 & 3) << 3;

  short8 kb8 = {}, vb8 = {};
  if (WIN) {
#pragma unroll
    for (int j = 0; j < 8; j++) {
      kb8[j] = (short)f2bf(qkvb[768 + nh * 64 + dv8s + j]);
      vb8[j] = (short)f2bf(qkvb[1536 + nh * 64 + dv8s + j]);
    }
  }

  auto load_kv = [&](int gk, short8& kv, short8& vv) {
    kv = short8{}; vv = short8{};
    if (gk < Ntok) {
      if (WIN) {
        const int rI = ridx[gk];
        if (rI != 0xFFFF) {
          const size_t a = base + (size_t)rI * 2304;
          kv = *(const short8*)&qkv[a + 768 + dv8s];
          vv = *(const short8*)&qkv[a + 1536 + dv8s];
        } else { kv = kb8; vv = vb8; }
      } else {
        const size_t a = base + (size_t)gk * 2304;
        kv = *(const short8*)&qkv[a + 768 + dv8s];
        vv = *(const short8*)&qkv[a + 1536 + dv8s];
      }
    }
  };

  short8 kpre, vpre;
  load_kv(srow, kpre, vpre);

  for (int kt = 0; kt < nkt; kt++) {
    __syncthreads();
    {
      const int row = srow;
      *(short8*)&Ks[(row * 64 + dv8s) ^ ((row & 7) << 3)] = kpre;
      const int kcol = row ^ vswz;
#pragma unroll
      for (int j = 0; j < 8; j++)
        Vst[(dv8s + j) * 40 + kcol] = (ushort_t)vpre[j];
    }
    if (kt + 1 < nkt) load_kv((kt + 1) * 32 + srow, kpre, vpre);
    __syncthreads();

    f32x4 c[2] = {};
    __builtin_amdgcn_s_setprio(1);
#pragma unroll
    for (int kb = 0; kb < 2; kb++)
#pragma unroll
      for (int ct = 0; ct < 2; ct++) {
        const int krow = ct * 16 + lx;
        short8 kf = *(const short8*)&Ks[(krow * 64 + kb * 32 + ly * 8) ^ ((krow & 7) << 3)];
        c[ct] = __builtin_amdgcn_mfma_f32_16x16x32_bf16(qa[kb], kf, c[ct], 0, 0, 0);
      }
    __builtin_amdgcn_s_setprio(0);

    const int k0a = kt * 32 + lx, k1a = k0a + 16;
    const int tv0 = khw[min(k0a, 1023)], tv1 = khw[min(k1a, 1023)];
    const int kh0 = tv0 >> 8, kw0 = tv0 & 255;
    const int kh1 = tv1 >> 8, kw1 = tv1 & 255;
    float pv0[4], pv1[4], mt[4];
#pragma unroll
    for (int r = 0; r < 4; r++) {
      const int trow = (wave * 16 + ly * 4 + r) * 66;
      float s0 = c[0][r] * 0.125f + bf2f(Th[trow + qh_r[r] - kh0 + Hd - 1])
               + bf2f(Tw[trow + qw_r[r] - kw0 + Wd - 1]);
      float s1 = c[1][r] * 0.125f + bf2f(Th[trow + qh_r[r] - kh1 + Hd - 1])
               + bf2f(Tw[trow + qw_r[r] - kw1 + Wd - 1]);
      if (k0a >= Ntok) s0 = -1e30f;
      if (k1a >= Ntok) s1 = -1e30f;
      pv0[r] = s0; pv1[r] = s1;
      mt[r] = fmaxf(s0, s1);
    }
    const float dmax = fmaxf(fmaxf(mt[0] - m_[0], mt[1] - m_[1]),
                             fmaxf(mt[2] - m_[2], mt[3] - m_[3]));
    if (!__all(dmax <= 8.f)) {
#pragma unroll
      for (int r = 0; r < 4; r++) {
        float mr = mt[r];
#pragma unroll
        for (int off = 1; off <= 8; off <<= 1) mr = fmaxf(mr, __shfl_xor(mr, off));
        const float mn = fmaxf(m_[r], mr);
        const float sc = __expf(m_[r] - mn);
        m_[r] = mn; l_[r] *= sc;
#pragma unroll
        for (int dt = 0; dt < 4; dt++) o[dt][r] *= sc;
      }
    }
#pragma unroll
    for (int r = 0; r < 4; r++) {
      const float p0 = __expf(pv0[r] - m_[r]);
      const float p1 = __expf(pv1[r] - m_[r]);
      l_[r] += p0 + p1;
      const int pb = wave * 640 + (ly * 4 + r) * 40;
      Ps[pb + lx]      = f2bf(p0);
      Ps[pb + 16 + lx] = f2bf(p1);
    }
    short8 pf = *(const short8*)&Ps[wave * 640 + lx * 40 + ly * 8];
    __builtin_amdgcn_s_setprio(1);
#pragma unroll
    for (int dt = 0; dt < 4; dt++) {
      const int drow = dt * 16 + lx;
      short8 vf = *(const short8*)&Vst[drow * 40 + ((ly * 8) ^ (((drow >> 3) & 3) << 3))];
      o[dt] = __builtin_amdgcn_mfma_f32_16x16x32_bf16(pf, vf, o[dt], 0, 0, 0);
    }
    __builtin_amdgcn_s_setprio(0);
  }

#pragma unroll
  for (int r = 0; r < 4; r++) {
#pragma unroll
    for (int off = 1; off <= 8; off <<= 1) l_[r] += __shfl_xor(l_[r], off);
    const int qq = q0 + wave * 16 + ly * 4 + r;
    if (qq >= Ntok) continue;
    const size_t orow = WIN ? ((size_t)wb * NW + qq) : ((size_t)b_img * NTOK + qq);
    const float inv = 1.f / l_[r];
#pragma unroll
    for (int dt = 0; dt < 4; dt++)
      out[orow * E + nh * 64 + dt * 16 + lx] = f2bf(o[dt][r] * inv);
  }
}

// ---------------- im2col ----------------
__global__ __launch_bounds__(256) void im2col(const float* __restrict__ x,
                                              ushort_t* __restrict__ out) {
  const int blk = blockIdx.x;
  const int b = blk >> 10, t = blk & 1023, gy = t >> 5, gx = t & 31;
  for (int k = threadIdx.x; k < 768; k += 256) {
    const int ci = k >> 8, rem = k & 255, py = rem >> 4, px = rem & 15;
    out[(size_t)blk * 768 + k] =
        f2bf(x[(((size_t)b * 3 + ci) * 512 + gy * 16 + py) * 512 + gx * 16 + px]);
  }
}

// ---------------- ALL-layer weight transpose, 64x64 tiles ----------------
__global__ __launch_bounds__(256) void prep_all(
    const float* __restrict__ qkvw, const float* __restrict__ projw,
    const float* __restrict__ fc1w, const float* __restrict__ fc2w,
    ushort_t* __restrict__ wqA, ushort_t* __restrict__ wpA,
    ushort_t* __restrict__ w1A, ushort_t* __restrict__ w2A) {
  __shared__ float tile[64][65];
  int blk = blockIdx.x;
  const int l = blk / 1728; blk -= l * 1728;
  const float* W; ushort_t* Wt; int Kd, Nd, tn, tk;
  if (blk < 432)       { W = qkvw + (size_t)l * 768 * 2304; Wt = wqA + (size_t)l * 2304 * 768;
                         Kd = 768;  Nd = 2304; tn = blk % 36;          tk = blk / 36; }
  else if (blk < 576)  { W = projw + (size_t)l * 768 * 768; Wt = wpA + (size_t)l * 768 * 768;
                         Kd = 768;  Nd = 768;  tn = (blk - 432) % 12;  tk = (blk - 432) / 12; }
  else if (blk < 1152) { W = fc1w + (size_t)l * 768 * 3072; Wt = w1A + (size_t)l * 3072 * 768;
                         Kd = 768;  Nd = 3072; tn = (blk - 576) % 48;  tk = (blk - 576) / 48; }
  else                 { W = fc2w + (size_t)l * 3072 * 768; Wt = w2A + (size_t)l * 768 * 3072;
                         Kd = 3072; Nd = 768;  tn = (blk - 1152) % 12; tk = (blk - 1152) / 12; }
  const int k0 = tk * 64, n0 = tn * 64;
  const int kr = threadIdx.x >> 2, cg = (threadIdx.x & 3) * 16;
  const float* src = &W[(size_t)(k0 + kr) * Nd + n0 + cg];
#pragma unroll
  for (int j = 0; j < 4; j++) {
    const float4 v = *(const float4*)&src[j * 4];
    tile[kr][cg + j * 4 + 0] = v.x;
    tile[kr][cg + j * 4 + 1] = v.y;
    tile[kr][cg + j * 4 + 2] = v.z;
    tile[kr][cg + j * 4 + 3] = v.w;
  }
  __syncthreads();
  const int nr = kr;
  short8 o0, o1;
#pragma unroll
  for (int j = 0; j < 8; j++) o0[j] = (short)f2bf(tile[cg + j][nr]);
#pragma unroll
  for (int j = 0; j < 8; j++) o1[j] = (short)f2bf(tile[cg + 8 + j][nr]);
  ushort_t* dst = &Wt[(size_t)(n0 + nr) * Kd + k0 + cg];
  *(short8*)&dst[0] = o0;
  *(short8*)&dst[8] = o1;
}

// ---------------- elementwise fp32 -> bf16 ----------------
__global__ __launch_bounds__(256) void cast_bf16(const float* __restrict__ in,
                                                 ushort_t* __restrict__ out, int n) {
  const int idx = (blockIdx.x * 256 + threadIdx.x) * 4;
  if (idx + 3 < n) {
    const float4 v = *(const float4*)&in[idx];
    ushort4 p;
    p.x = f2bf(v.x); p.y = f2bf(v.y); p.z = f2bf(v.z); p.w = f2bf(v.w);
    *(ushort4*)&out[idx] = p;
  }
}

// ---------------- launch ----------------
extern "C" void kernel_launch(void* const* d_in, const int* in_sizes, int n_in,
                              void* d_out, int out_size, void* d_ws, size_t ws_size,
                              hipStream_t stream) {
  const float* x_in     = (const float*)d_in[0];
  const float* patch_w  = (const float*)d_in[1];
  const float* patch_b  = (const float*)d_in[2];
  const float* pos_emb  = (const float*)d_in[3];
  const float* ln1_w    = (const float*)d_in[4];
  const float* ln1_b    = (const float*)d_in[5];
  const float* qkv_w    = (const float*)d_in[6];
  const float* qkv_b    = (const float*)d_in[7];
  const float* proj_w   = (const float*)d_in[8];
  const float* proj_b   = (const float*)d_in[9];
  const float* rel_h_w  = (const float*)d_in[10];
  const float* rel_w_w  = (const float*)d_in[11];
  const float* rel_h_g  = (const float*)d_in[12];
  const float* rel_w_g  = (const float*)d_in[13];
  const float* ln2_w    = (const float*)d_in[14];
  const float* ln2_b    = (const float*)d_in[15];
  const float* fc1_w    = (const float*)d_in[16];
  const float* fc1_b    = (const float*)d_in[17];
  const float* fc2_w    = (const float*)d_in[18];
  const float* fc2_b    = (const float*)d_in[19];
  const float* out_w    = (const float*)d_in[20];
  const float* out_b    = (const float*)d_in[21];
  float* outp = (float*)d_out;

  float* xbuf = (float*)d_ws;                                  // 2048*768 f32
  ushort_t* hb16    = (ushort_t*)(xbuf + (size_t)ROWS * E);    // 2048*768
  ushort_t* qkvimg  = hb16 + (size_t)ROWS * E;                 // 2048*2304
  ushort_t* attnw16 = qkvimg + (size_t)ROWS * 3 * E;           // 3528*768
  ushort_t* h1b16   = attnw16 + (size_t)WROWS * E;             // 2048*3072
  ushort_t* wqA     = h1b16 + (size_t)ROWS * 4 * E;            // 12*2304*768
  ushort_t* wpA     = wqA + (size_t)12 * 2304 * 768;           // 12*768*768
  ushort_t* w1A     = wpA + (size_t)12 * 768 * 768;            // 12*3072*768
  ushort_t* w2A     = w1A + (size_t)12 * 3072 * 768;           // 12*768*3072
  ushort_t* pwT16   = w2A + (size_t)12 * 768 * 3072;           // 768*768
  ushort_t* headW16 = pwT16 + (size_t)768 * 768;               // 256*768
  ushort_t* imb16 = hb16;

  // ---- one-shot weight prep (all 12 layers) + casts ----
  prep_all<<<12 * 1728, 256, 0, stream>>>(qkv_w, proj_w, fc1_w, fc2_w,
                                          wqA, wpA, w1A, w2A);
  cast_bf16<<<576, 256, 0, stream>>>(patch_w, pwT16, 768 * 768);
  cast_bf16<<<192, 256, 0, stream>>>(out_w, headW16, 256 * 768);

  // ---- patch embed as GEMM ----
  im2col<<<ROWS, 256, 0, stream>>>(x_in, imb16);
  gemm_32<OP_POS, 0><<<768, 128, 0, stream>>>(
      imb16, pwT16, patch_b, nullptr, pos_emb, xbuf, ROWS, E, E, 12);

  int win_i = 0, glob_i = 0;
  for (int i = 0; i < 12; i++) {
    const bool is_win = (WIN_MASK >> i) & 1;
    const ushort_t* wq = wqA + (size_t)i * 2304 * 768;
    const ushort_t* wp = wpA + (size_t)i * 768 * 768;
    const ushort_t* w1 = w1A + (size_t)i * 3072 * 768;
    const ushort_t* w2 = w2A + (size_t)i * 768 * 3072;

    ln_kernel<<<ROWS / 4, 256, 0, stream>>>(xbuf, ln1_w + i * E, ln1_b + i * E, hb16);

    gemm_bt<OP_QKV, 0><<<36 * 32, 256, 0, stream>>>(
        hb16, wq, qkv_b + i * 3 * E, nullptr, nullptr, qkvimg, ROWS, 3 * E, E, 36);

    if (is_win) {
      attn64<1><<<dim3(4, BW * NH), 256, 0, stream>>>(
          qkvimg, attnw16, rel_h_w + (size_t)win_i * (2 * WS - 1) * HD,
          rel_w_w + (size_t)win_i * (2 * WS - 1) * HD, qkv_b + i * 3 * E, WS, WS);
      win_i++;
      gemm_32<OP_ADD, 2><<<768, 128, 0, stream>>>(
          attnw16, wp, proj_b + i * E, xbuf, nullptr, xbuf, ROWS, E, E, 12);
    } else {
      attn64<0><<<dim3(16, Bsz * NH), 256, 0, stream>>>(
          qkvimg, attnw16, rel_h_g + (size_t)glob_i * (2 * G - 1) * HD,
          rel_w_g + (size_t)glob_i * (2 * G - 1) * HD, qkv_b + i * 3 * E, G, G);
      glob_i++;
      gemm_32<OP_ADD, 0><<<768, 128, 0, stream>>>(
          attnw16, wp, proj_b + i * E, xbuf, nullptr, xbuf, ROWS, E, E, 12);
    }

    ln_kernel<<<ROWS / 4, 256, 0, stream>>>(xbuf, ln2_w + i * E, ln2_b + i * E, hb16);
    gemm_bt<OP_GELU, 0><<<48 * 32, 256, 0, stream>>>(
        hb16, w1, fc1_b + i * 4 * E, nullptr, nullptr, h1b16, ROWS, 4 * E, E, 48);
    gemm_32<OP_ADD, 0><<<768, 128, 0, stream>>>(
        h1b16, w2, fc2_b + i * E, xbuf, nullptr, xbuf, ROWS, E, 4 * E, 12);
  }

  // ---- head ----
  cast_bf16<<<1536, 256, 0, stream>>>(xbuf, hb16, ROWS * E);
  gemm_32<OP_HEAD, 0><<<256, 128, 0, stream>>>(
      hb16, headW16, out_b, nullptr, nullptr, outp, ROWS, 256, E, 4);
}

// Round 16
// 1716.773 us; speedup vs baseline: 1.0873x; 1.0873x over previous
//
#include <hip/hip_runtime.h>
#include <hip/hip_bf16.h>
#include <math.h>

// ---------------- constants ----------------
static constexpr int E   = 768;
static constexpr int NH  = 12;
static constexpr int HD  = 64;
static constexpr int Bsz = 2;
static constexpr int G   = 32;
static constexpr int NTOK = G * G;      // 1024
static constexpr int ROWS = Bsz * NTOK; // 2048
static constexpr int WS  = 14;
static constexpr int NWIN_SIDE = 3;
static constexpr int NWIN = NWIN_SIDE * NWIN_SIDE;
static constexpr int BW  = Bsz * NWIN;   // 18
static constexpr int NW  = WS * WS;      // 196
static constexpr int WROWS = BW * NW;    // 3528
static constexpr int WIN_MASK = 0x6DB;

typedef __attribute__((ext_vector_type(8))) short short8;
typedef __attribute__((ext_vector_type(4))) float f32x4;
typedef unsigned short ushort_t;

__device__ __forceinline__ unsigned short f2bf(float x) {
  union { float f; unsigned u; } v; v.f = x;
  unsigned r = v.u + 0x7fffu + ((v.u >> 16) & 1u);
  return (unsigned short)(r >> 16);
}
__device__ __forceinline__ float bf2f(unsigned short h) {
  union { unsigned u; float f; } v; v.u = ((unsigned)h) << 16;
  return v.f;
}

__device__ __forceinline__ void glds16(const void* g, void* l) {
  __builtin_amdgcn_global_load_lds(
      (const __attribute__((address_space(1))) unsigned*)g,
      (__attribute__((address_space(3))) unsigned*)l, 16, 0, 0);
}

// ---------------- LayerNorm fp32 -> bf16, one wave per row ----------------
__global__ __launch_bounds__(256) void ln_kernel(
    const float* __restrict__ in, const float* __restrict__ w,
    const float* __restrict__ b, ushort_t* __restrict__ out) {
  const int wave = threadIdx.x >> 6, lane = threadIdx.x & 63;
  const int row = blockIdx.x * 4 + wave;
  const float4* r4 = (const float4*)(in + (size_t)row * E);
  float4 v[3];
  v[0] = r4[lane]; v[1] = r4[lane + 64]; v[2] = r4[lane + 128];
  float s = 0.f, s2 = 0.f;
#pragma unroll
  for (int i = 0; i < 3; i++) {
    s += v[i].x + v[i].y + v[i].z + v[i].w;
    s2 += v[i].x * v[i].x + v[i].y * v[i].y + v[i].z * v[i].z + v[i].w * v[i].w;
  }
#pragma unroll
  for (int off = 1; off <= 32; off <<= 1) {
    s += __shfl_xor(s, off);
    s2 += __shfl_xor(s2, off);
  }
  const float mean = s * (1.f / E);
  const float var  = s2 * (1.f / E) - mean * mean;
  const float rs   = rsqrtf(var + 1e-6f);
  ushort_t* o = out + (size_t)row * E;
#pragma unroll
  for (int i = 0; i < 3; i++) {
    const int e0 = (lane + i * 64) * 4;
    ushort4 p;
    p.x = f2bf((v[i].x - mean) * rs * w[e0]     + b[e0]);
    p.y = f2bf((v[i].y - mean) * rs * w[e0 + 1] + b[e0 + 1]);
    p.z = f2bf((v[i].z - mean) * rs * w[e0 + 2] + b[e0 + 2]);
    p.w = f2bf((v[i].w - mean) * rs * w[e0 + 3] + b[e0 + 3]);
    *(ushort4*)&o[e0] = p;
  }
}

enum { OP_QKV = 0, OP_GELU = 1, OP_ADD = 2, OP_POS = 3, OP_HEAD = 4 };

// ---------------- bf16 GEMM, 64x64 tile, 4 waves, counted-vmcnt 2-phase ----
template <int OP, int MAP>
__global__ __launch_bounds__(256) void gemm_bt(
    const ushort_t* __restrict__ A, const ushort_t* __restrict__ Bt,
    const float* __restrict__ bias, const float* __restrict__ res,
    const float* __restrict__ pos, void* __restrict__ Cp,
    int M, int N, int K, int ncol) {
  __shared__ ushort_t As[2][64 * 64];
  __shared__ ushort_t Bs[2][64 * 64];
  const int tid = threadIdx.x, wave = tid >> 6, lane = tid & 63;
  const int lx = lane & 15, ly = lane >> 4;

  const int nwg = gridDim.x;
  const int q = nwg >> 3, r = nwg & 7;
  const int xcd = blockIdx.x & 7, loc = blockIdx.x >> 3;
  const int wgid = ((xcd < r) ? xcd * (q + 1) : r * (q + 1) + (xcd - r) * q) + loc;
  const int brow = wgid / ncol, bcol = wgid - brow * ncol;
  const int row0 = brow * 64, col0 = bcol * 64;
  const int wm = (wave >> 1) * 32, wn = (wave & 1) * 32;
  const int rin = lane >> 3, pseg = lane & 7;
  const int lseg = pseg ^ rin;
  f32x4 acc[2][2] = {};

  const ushort_t* aptr[2];
  const ushort_t* bptr[2];
#pragma unroll
  for (int j = 0; j < 2; j++) {
    const int slot = wave * 2 + j;
    int ar = row0 + slot * 8 + rin;
    if (ar >= M) ar = M - 1;
    if (MAP == 2) {
      const int bI = ar >> 10, t = ar & 1023, y = t >> 5, x = t & 31;
      const int by = y / WS, wy = y - by * WS;
      const int bx = x / WS, wx = x - bx * WS;
      const int win = bI * NWIN + by * NWIN_SIDE + bx;
      aptr[j] = &A[((size_t)win * NW + wy * WS + wx) * E + lseg * 8];
    } else {
      aptr[j] = &A[(size_t)ar * K + lseg * 8];
    }
    const int br = col0 + slot * 8 + rin;
    bptr[j] = &Bt[(size_t)br * K + lseg * 8];
  }

#pragma unroll
  for (int j = 0; j < 2; j++) {
    const int slot = wave * 2 + j;
    glds16(aptr[j], &As[0][slot * 512]);
    glds16(bptr[j], &Bs[0][slot * 512]);
  }

  const int nt = K >> 6;
  for (int t = 0; t < nt; t++) {
    const int cur = t & 1;
    if (t + 1 < nt) {
      const int k1 = (t + 1) << 6;
#pragma unroll
      for (int j = 0; j < 2; j++) {
        const int slot = wave * 2 + j;
        glds16(aptr[j] + k1, &As[cur ^ 1][slot * 512]);
        glds16(bptr[j] + k1, &Bs[cur ^ 1][slot * 512]);
      }
      asm volatile("s_waitcnt vmcnt(4)" ::: "memory");
    } else {
      asm volatile("s_waitcnt vmcnt(0)" ::: "memory");
    }
    __builtin_amdgcn_s_barrier();
    __builtin_amdgcn_sched_barrier(0);
#pragma unroll
    for (int kb = 0; kb < 2; kb++) {
      short8 af[2], bfm[2];
#pragma unroll
      for (int m = 0; m < 2; m++) {
        const int rr = wm + m * 16 + lx;
        af[m] = *(const short8*)&As[cur][rr * 64 + (((kb * 4 + ly) ^ (rr & 7)) * 8)];
      }
#pragma unroll
      for (int n = 0; n < 2; n++) {
        const int rr = wn + n * 16 + lx;
        bfm[n] = *(const short8*)&Bs[cur][rr * 64 + (((kb * 4 + ly) ^ (rr & 7)) * 8)];
      }
      __builtin_amdgcn_s_setprio(1);
#pragma unroll
      for (int m = 0; m < 2; m++)
#pragma unroll
        for (int n = 0; n < 2; n++)
          acc[m][n] = __builtin_amdgcn_mfma_f32_16x16x32_bf16(af[m], bfm[n], acc[m][n], 0, 0, 0);
      __builtin_amdgcn_s_setprio(0);
    }
    asm volatile("s_waitcnt lgkmcnt(0)" ::: "memory");
    __builtin_amdgcn_s_barrier();
    __builtin_amdgcn_sched_barrier(0);
  }

#pragma unroll
  for (int m = 0; m < 2; m++) {
#pragma unroll
    for (int r4 = 0; r4 < 4; r4++) {
      const int gr = row0 + wm + m * 16 + ly * 4 + r4;
      if (gr >= M) continue;
#pragma unroll
      for (int n = 0; n < 2; n++) {
        const int gc = col0 + wn + n * 16 + lx;
        float v = acc[m][n][r4] + bias[gc];
        if (OP == OP_GELU) v = 0.5f * v * (1.f + erff(v * 0.70710678118654752f));
        if (OP == OP_ADD)  v += res[(size_t)gr * N + gc];
        if (OP == OP_POS)  v += pos[(size_t)(gr & 1023) * N + gc];
        if (OP == OP_QKV || OP == OP_GELU)
          ((ushort_t*)Cp)[(size_t)gr * N + gc] = f2bf(v);
        else if (OP == OP_HEAD)
          ((float*)Cp)[(((size_t)(gr >> 10) * 256 + gc) << 10) | (gr & 1023)] = v;
        else
          ((float*)Cp)[(size_t)gr * N + gc] = v;
      }
    }
  }
}

// ---------------- bf16 GEMM, 32x64 tile, 2 waves, for small-N GEMMs --------
template <int OP, int MAP>
__global__ __launch_bounds__(128) void gemm_32(
    const ushort_t* __restrict__ A, const ushort_t* __restrict__ Bt,
    const float* __restrict__ bias, const float* __restrict__ res,
    const float* __restrict__ pos, void* __restrict__ Cp,
    int M, int N, int K, int ncol) {
  __shared__ ushort_t As[2][32 * 64];
  __shared__ ushort_t Bs[2][64 * 64];
  const int tid = threadIdx.x, wave = tid >> 6, lane = tid & 63;
  const int lx = lane & 15, ly = lane >> 4;

  const int nwg = gridDim.x;
  const int q = nwg >> 3, r = nwg & 7;
  const int xcd = blockIdx.x & 7, loc = blockIdx.x >> 3;
  const int wgid = ((xcd < r) ? xcd * (q + 1) : r * (q + 1) + (xcd - r) * q) + loc;
  const int brow = wgid / ncol, bcol = wgid - brow * ncol;
  const int row0 = brow * 32, col0 = bcol * 64;
  const int wn = wave * 32;
  const int rin = lane >> 3, pseg = lane & 7;
  const int lseg = pseg ^ rin;
  f32x4 acc[2][2] = {};

  const ushort_t* aptr[2];
  const ushort_t* bptr[4];
#pragma unroll
  for (int j = 0; j < 2; j++) {
    const int slot = wave * 2 + j;
    int ar = row0 + slot * 8 + rin;
    if (ar >= M) ar = M - 1;
    if (MAP == 2) {
      const int bI = ar >> 10, t = ar & 1023, y = t >> 5, x = t & 31;
      const int by = y / WS, wy = y - by * WS;
      const int bx = x / WS, wx = x - bx * WS;
      const int win = bI * NWIN + by * NWIN_SIDE + bx;
      aptr[j] = &A[((size_t)win * NW + wy * WS + wx) * E + lseg * 8];
    } else {
      aptr[j] = &A[(size_t)ar * K + lseg * 8];
    }
  }
#pragma unroll
  for (int j = 0; j < 4; j++) {
    const int slot = wave * 4 + j;
    const int br = col0 + slot * 8 + rin;
    bptr[j] = &Bt[(size_t)br * K + lseg * 8];
  }

#pragma unroll
  for (int j = 0; j < 2; j++) glds16(aptr[j], &As[0][(wave * 2 + j) * 512]);
#pragma unroll
  for (int j = 0; j < 4; j++) glds16(bptr[j], &Bs[0][(wave * 4 + j) * 512]);

  const int nt = K >> 6;
  for (int t = 0; t < nt; t++) {
    const int cur = t & 1;
    if (t + 1 < nt) {
      const int k1 = (t + 1) << 6;
#pragma unroll
      for (int j = 0; j < 2; j++) glds16(aptr[j] + k1, &As[cur ^ 1][(wave * 2 + j) * 512]);
#pragma unroll
      for (int j = 0; j < 4; j++) glds16(bptr[j] + k1, &Bs[cur ^ 1][(wave * 4 + j) * 512]);
      asm volatile("s_waitcnt vmcnt(6)" ::: "memory");
    } else {
      asm volatile("s_waitcnt vmcnt(0)" ::: "memory");
    }
    __builtin_amdgcn_s_barrier();
    __builtin_amdgcn_sched_barrier(0);
#pragma unroll
    for (int kb = 0; kb < 2; kb++) {
      short8 af[2], bfm[2];
#pragma unroll
      for (int m = 0; m < 2; m++) {
        const int rr = m * 16 + lx;
        af[m] = *(const short8*)&As[cur][rr * 64 + (((kb * 4 + ly) ^ (rr & 7)) * 8)];
      }
#pragma unroll
      for (int n = 0; n < 2; n++) {
        const int rr = wn + n * 16 + lx;
        bfm[n] = *(const short8*)&Bs[cur][rr * 64 + (((kb * 4 + ly) ^ (rr & 7)) * 8)];
      }
      __builtin_amdgcn_s_setprio(1);
#pragma unroll
      for (int m = 0; m < 2; m++)
#pragma unroll
        for (int n = 0; n < 2; n++)
          acc[m][n] = __builtin_amdgcn_mfma_f32_16x16x32_bf16(af[m], bfm[n], acc[m][n], 0, 0, 0);
      __builtin_amdgcn_s_setprio(0);
    }
    asm volatile("s_waitcnt lgkmcnt(0)" ::: "memory");
    __builtin_amdgcn_s_barrier();
    __builtin_amdgcn_sched_barrier(0);
  }

#pragma unroll
  for (int m = 0; m < 2; m++) {
#pragma unroll
    for (int r4 = 0; r4 < 4; r4++) {
      const int gr = row0 + m * 16 + ly * 4 + r4;
      if (gr >= M) continue;
#pragma unroll
      for (int n = 0; n < 2; n++) {
        const int gc = col0 + wn + n * 16 + lx;
        float v = acc[m][n][r4] + bias[gc];
        if (OP == OP_GELU) v = 0.5f * v * (1.f + erff(v * 0.70710678118654752f));
        if (OP == OP_ADD)  v += res[(size_t)gr * N + gc];
        if (OP == OP_POS)  v += pos[(size_t)(gr & 1023) * N + gc];
        if (OP == OP_QKV || OP == OP_GELU)
          ((ushort_t*)Cp)[(size_t)gr * N + gc] = f2bf(v);
        else if (OP == OP_HEAD)
          ((float*)Cp)[(((size_t)(gr >> 10) * 256 + gc) << 10) | (gr & 1023)] = v;
        else
          ((float*)Cp)[(size_t)gr * N + gc] = v;
      }
    }
  }
}

// ---------------- MFMA flash attention, 4 waves x 64 queries ----------------
template <int WIN>
__global__ __launch_bounds__(256) void attn64(
    const ushort_t* __restrict__ qkv, ushort_t* __restrict__ out,
    const float* __restrict__ relh, const float* __restrict__ relw,
    const float* __restrict__ qkvb, int Hd, int Wd) {
  const int Ntok = Hd * Wd;  // 196 or 1024
  __shared__ ushort_t smem[17664];
  ushort_t* Ks   = smem;           // main [0,2048): 32x64 swizzled
  ushort_t* Vst  = smem + 2048;    // main [2048,4608): [64][40]
  ushort_t* Qs   = smem;           // prologue [0,4096)
  ushort_t* RelS = smem;           // prologue phase 2 [0,4096)
  ushort_t* Ps   = smem + 4608;    // [4][16][40]
  ushort_t* Th   = smem + 7168;    // [64][66]
  ushort_t* Tw   = smem + 11392;   // [64][66]
  ushort_t* khw  = smem + 15616;   // [1024]
  ushort_t* ridx = smem + 16640;   // [1024]

  const int tid = threadIdx.x, wave = tid >> 6, lane = tid & 63;
  const int lx = lane & 15, ly = lane >> 4;
  const int bh = blockIdx.y;
  const int nh = bh % NH, wb = bh / NH;
  int by = 0, bx = 0, b_img;
  if (WIN) {
    b_img = wb / NWIN;
    const int wr = wb - b_img * NWIN;
    by = wr / NWIN_SIDE; bx = wr - by * NWIN_SIDE;
  } else {
    b_img = wb;
  }
  const int q0 = blockIdx.x * 64;
  const size_t base = (size_t)b_img * NTOK * 2304 + nh * 64;

  for (int k = tid; k < 1024; k += 256) {
    const int kc = min(k, Ntok - 1);
    const int kh = kc / Wd, kw = kc - kh * Wd;
    khw[k] = (ushort_t)((kh << 8) | kw);
    if (WIN) {
      const int gy = by * WS + kh, gx = bx * WS + kw;
      ridx[k] = (gy < G && gx < G) ? (ushort_t)(gy * G + gx) : (ushort_t)0xFFFF;
    }
  }
  __syncthreads();

#pragma unroll
  for (int i = 0; i < 2; i++) {
    const int fv = i * 256 + tid;
    const int row = fv >> 3, dv8 = (fv & 7) * 8;
    const int qq = min(q0 + row, Ntok - 1);
    int rI;
    if (WIN) {
      const int t = ridx[qq];
      rI = (t == 0xFFFF) ? 0 : t;
    } else {
      rI = qq;
    }
    short8 v = *(const short8*)&qkv[base + (size_t)rI * 2304 + dv8];
    *(short8*)&Qs[(row * 64 + dv8) ^ ((row & 7) << 3)] = v;
  }
  __syncthreads();

  short8 qa[2];
  {
    const int row = wave * 16 + lx;
#pragma unroll
    for (int kb = 0; kb < 2; kb++)
      qa[kb] = *(const short8*)&Qs[(row * 64 + kb * 32 + ly * 8) ^ ((row & 7) << 3)];
  }
  int qh_r[4], qw_r[4];
#pragma unroll
  for (int r = 0; r < 4; r++) {
    const int qc = min(q0 + wave * 16 + ly * 4 + r, Ntok - 1);
    qh_r[r] = qc / Wd;
    qw_r[r] = qc - qh_r[r] * Wd;
  }
  __syncthreads();

  for (int t = 0; t < 2; t++) {
    const float* rel = t ? relw : relh;
    const int TR = t ? (2 * Wd - 1) : (2 * Hd - 1);
#pragma unroll
    for (int i = 0; i < 2; i++) {
      const int fv = i * 256 + tid;
      const int row = fv >> 3, c8 = (fv & 7) * 8;
      short8 v = {};
      if (row < TR) {
        const float* rp = &rel[(size_t)row * 64 + c8];
        const float4 a = *(const float4*)rp;
        const float4 bq = *(const float4*)(rp + 4);
        v[0] = (short)f2bf(a.x);  v[1] = (short)f2bf(a.y);
        v[2] = (short)f2bf(a.z);  v[3] = (short)f2bf(a.w);
        v[4] = (short)f2bf(bq.x); v[5] = (short)f2bf(bq.y);
        v[6] = (short)f2bf(bq.z); v[7] = (short)f2bf(bq.w);
      }
      *(short8*)&RelS[(row * 64 + c8) ^ ((row & 7) << 3)] = v;
    }
    __syncthreads();
    const int NT = (TR + 15) >> 4;
    ushort_t* T = t ? Tw : Th;
    for (int nt = 0; nt < NT; nt++) {
      f32x4 a = {};
      __builtin_amdgcn_s_setprio(1);
#pragma unroll
      for (int kb = 0; kb < 2; kb++) {
        const int rrow = nt * 16 + lx;
        short8 bfv = *(const short8*)&RelS[(rrow * 64 + kb * 32 + ly * 8) ^ ((rrow & 7) << 3)];
        a = __builtin_amdgcn_mfma_f32_16x16x32_bf16(qa[kb], bfv, a, 0, 0, 0);
      }
      __builtin_amdgcn_s_setprio(0);
#pragma unroll
      for (int reg = 0; reg < 4; reg++)
        T[(wave * 16 + ly * 4 + reg) * 66 + nt * 16 + lx] = f2bf(a[reg]);
    }
    __syncthreads();
  }

  f32x4 o[4] = {};
  float m_[4], l_[4];
#pragma unroll
  for (int r = 0; r < 4; r++) { m_[r] = -3e38f; l_[r] = 0.f; }

  const int nkt = (Ntok + 31) >> 5;
  const int srow = tid >> 3, c7 = tid & 7, dv8s = c7 * 8;
  const int vswz = (c7 & 3) << 3;

  short8 kb8 = {}, vb8 = {};
  if (WIN) {
#pragma unroll
    for (int j = 0; j < 8; j++) {
      kb8[j] = (short)f2bf(qkvb[768 + nh * 64 + dv8s + j]);
      vb8[j] = (short)f2bf(qkvb[1536 + nh * 64 + dv8s + j]);
    }
  }

  auto load_kv = [&](int gk, short8& kv, short8& vv) {
    kv = short8{}; vv = short8{};
    if (gk < Ntok) {
      if (WIN) {
        const int rI = ridx[gk];
        if (rI != 0xFFFF) {
          const size_t a = base + (size_t)rI * 2304;
          kv = *(const short8*)&qkv[a + 768 + dv8s];
          vv = *(const short8*)&qkv[a + 1536 + dv8s];
        } else { kv = kb8; vv = vb8; }
      } else {
        const size_t a = base + (size_t)gk * 2304;
        kv = *(const short8*)&qkv[a + 768 + dv8s];
        vv = *(const short8*)&qkv[a + 1536 + dv8s];
      }
    }
  };

  short8 kpre, vpre;
  load_kv(srow, kpre, vpre);

  for (int kt = 0; kt < nkt; kt++) {
    __syncthreads();
    {
      const int row = srow;
      *(short8*)&Ks[(row * 64 + dv8s) ^ ((row & 7) << 3)] = kpre;
      const int kcol = row ^ vswz;
#pragma unroll
      for (int j = 0; j < 8; j++)
        Vst[(dv8s + j) * 40 + kcol] = (ushort_t)vpre[j];
    }
    if (kt + 1 < nkt) load_kv((kt + 1) * 32 + srow, kpre, vpre);
    __syncthreads();

    f32x4 c[2] = {};
    __builtin_amdgcn_s_setprio(1);
#pragma unroll
    for (int kb = 0; kb < 2; kb++)
#pragma unroll
      for (int ct = 0; ct < 2; ct++) {
        const int krow = ct * 16 + lx;
        short8 kf = *(const short8*)&Ks[(krow * 64 + kb * 32 + ly * 8) ^ ((krow & 7) << 3)];
        c[ct] = __builtin_amdgcn_mfma_f32_16x16x32_bf16(qa[kb], kf, c[ct], 0, 0, 0);
      }
    __builtin_amdgcn_s_setprio(0);

    const int k0a = kt * 32 + lx, k1a = k0a + 16;
    const int tv0 = khw[min(k0a, 1023)], tv1 = khw[min(k1a, 1023)];
    const int kh0 = tv0 >> 8, kw0 = tv0 & 255;
    const int kh1 = tv1 >> 8, kw1 = tv1 & 255;
    float pv0[4], pv1[4], mt[4];
#pragma unroll
    for (int r = 0; r < 4; r++) {
      const int trow = (wave * 16 + ly * 4 + r) * 66;
      float s0 = c[0][r] * 0.125f + bf2f(Th[trow + qh_r[r] - kh0 + Hd - 1])
               + bf2f(Tw[trow + qw_r[r] - kw0 + Wd - 1]);
      float s1 = c[1][r] * 0.125f + bf2f(Th[trow + qh_r[r] - kh1 + Hd - 1])
               + bf2f(Tw[trow + qw_r[r] - kw1 + Wd - 1]);
      if (k0a >= Ntok) s0 = -1e30f;
      if (k1a >= Ntok) s1 = -1e30f;
      pv0[r] = s0; pv1[r] = s1;
      mt[r] = fmaxf(s0, s1);
    }
    const float dmax = fmaxf(fmaxf(mt[0] - m_[0], mt[1] - m_[1]),
                             fmaxf(mt[2] - m_[2], mt[3] - m_[3]));
    if (!__all(dmax <= 8.f)) {
#pragma unroll
      for (int r = 0; r < 4; r++) {
        float mr = mt[r];
#pragma unroll
        for (int off = 1; off <= 8; off <<= 1) mr = fmaxf(mr, __shfl_xor(mr, off));
        const float mn = fmaxf(m_[r], mr);
        const float sc = __expf(m_[r] - mn);
        m_[r] = mn; l_[r] *= sc;
#pragma unroll
        for (int dt = 0; dt < 4; dt++) o[dt][r] *= sc;
      }
    }
#pragma unroll
    for (int r = 0; r < 4; r++) {
      const float p0 = __expf(pv0[r] - m_[r]);
      const float p1 = __expf(pv1[r] - m_[r]);
      l_[r] += p0 + p1;
      const int pb = wave * 640 + (ly * 4 + r) * 40;
      Ps[pb + lx]      = f2bf(p0);
      Ps[pb + 16 + lx] = f2bf(p1);
    }
    short8 pf = *(const short8*)&Ps[wave * 640 + lx * 40 + ly * 8];
    __builtin_amdgcn_s_setprio(1);
#pragma unroll
    for (int dt = 0; dt < 4; dt++) {
      const int drow = dt * 16 + lx;
      short8 vf = *(const short8*)&Vst[drow * 40 + ((ly * 8) ^ (((drow >> 3) & 3) << 3))];
      o[dt] = __builtin_amdgcn_mfma_f32_16x16x32_bf16(pf, vf, o[dt], 0, 0, 0);
    }
    __builtin_amdgcn_s_setprio(0);
  }

#pragma unroll
  for (int r = 0; r < 4; r++) {
#pragma unroll
    for (int off = 1; off <= 8; off <<= 1) l_[r] += __shfl_xor(l_[r], off);
    const int qq = q0 + wave * 16 + ly * 4 + r;
    if (qq >= Ntok) continue;
    const size_t orow = WIN ? ((size_t)wb * NW + qq) : ((size_t)b_img * NTOK + qq);
    const float inv = 1.f / l_[r];
#pragma unroll
    for (int dt = 0; dt < 4; dt++)
      out[orow * E + nh * 64 + dt * 16 + lx] = f2bf(o[dt][r] * inv);
  }
}

// ---------------- im2col ----------------
__global__ __launch_bounds__(256) void im2col(const float* __restrict__ x,
                                              ushort_t* __restrict__ out) {
  const int blk = blockIdx.x;
  const int b = blk >> 10, t = blk & 1023, gy = t >> 5, gx = t & 31;
  for (int k = threadIdx.x; k < 768; k += 256) {
    const int ci = k >> 8, rem = k & 255, py = rem >> 4, px = rem & 15;
    out[(size_t)blk * 768 + k] =
        f2bf(x[(((size_t)b * 3 + ci) * 512 + gy * 16 + py) * 512 + gx * 16 + px]);
  }
}

// ---------------- per-layer weight transpose, 64x64 tiles ----------------
__global__ __launch_bounds__(256) void prep_wt64(
    const float* __restrict__ qkvw, const float* __restrict__ projw,
    const float* __restrict__ fc1w, const float* __restrict__ fc2w,
    ushort_t* __restrict__ wq, ushort_t* __restrict__ wp,
    ushort_t* __restrict__ w1, ushort_t* __restrict__ w2) {
  __shared__ float tile[64][65];
  const int blk = blockIdx.x;
  const float* W; ushort_t* Wt; int Kd, Nd, tn, tk;
  if (blk < 432)       { W = qkvw;  Wt = wq; Kd = 768;  Nd = 2304; tn = blk % 36;          tk = blk / 36; }
  else if (blk < 576)  { W = projw; Wt = wp; Kd = 768;  Nd = 768;  tn = (blk - 432) % 12;  tk = (blk - 432) / 12; }
  else if (blk < 1152) { W = fc1w;  Wt = w1; Kd = 768;  Nd = 3072; tn = (blk - 576) % 48;  tk = (blk - 576) / 48; }
  else                 { W = fc2w;  Wt = w2; Kd = 3072; Nd = 768;  tn = (blk - 1152) % 12; tk = (blk - 1152) / 12; }
  const int k0 = tk * 64, n0 = tn * 64;
  const int kr = threadIdx.x >> 2, cg = (threadIdx.x & 3) * 16;
  const float* src = &W[(size_t)(k0 + kr) * Nd + n0 + cg];
#pragma unroll
  for (int j = 0; j < 4; j++) {
    const float4 v = *(const float4*)&src[j * 4];
    tile[kr][cg + j * 4 + 0] = v.x;
    tile[kr][cg + j * 4 + 1] = v.y;
    tile[kr][cg + j * 4 + 2] = v.z;
    tile[kr][cg + j * 4 + 3] = v.w;
  }
  __syncthreads();
  const int nr = kr;
  short8 o0, o1;
#pragma unroll
  for (int j = 0; j < 8; j++) o0[j] = (short)f2bf(tile[cg + j][nr]);
#pragma unroll
  for (int j = 0; j < 8; j++) o1[j] = (short)f2bf(tile[cg + 8 + j][nr]);
  ushort_t* dst = &Wt[(size_t)(n0 + nr) * Kd + k0 + cg];
  *(short8*)&dst[0] = o0;
  *(short8*)&dst[8] = o1;
}

// ---------------- elementwise fp32 -> bf16 ----------------
__global__ __launch_bounds__(256) void cast_bf16(const float* __restrict__ in,
                                                 ushort_t* __restrict__ out, int n) {
  const int idx = (blockIdx.x * 256 + threadIdx.x) * 4;
  if (idx + 3 < n) {
    const float4 v = *(const float4*)&in[idx];
    ushort4 p;
    p.x = f2bf(v.x); p.y = f2bf(v.y); p.z = f2bf(v.z); p.w = f2bf(v.w);
    *(ushort4*)&out[idx] = p;
  }
}

// ---------------- launch ----------------
extern "C" void kernel_launch(void* const* d_in, const int* in_sizes, int n_in,
                              void* d_out, int out_size, void* d_ws, size_t ws_size,
                              hipStream_t stream) {
  const float* x_in     = (const float*)d_in[0];
  const float* patch_w  = (const float*)d_in[1];
  const float* patch_b  = (const float*)d_in[2];
  const float* pos_emb  = (const float*)d_in[3];
  const float* ln1_w    = (const float*)d_in[4];
  const float* ln1_b    = (const float*)d_in[5];
  const float* qkv_w    = (const float*)d_in[6];
  const float* qkv_b    = (const float*)d_in[7];
  const float* proj_w   = (const float*)d_in[8];
  const float* proj_b   = (const float*)d_in[9];
  const float* rel_h_w  = (const float*)d_in[10];
  const float* rel_w_w  = (const float*)d_in[11];
  const float* rel_h_g  = (const float*)d_in[12];
  const float* rel_w_g  = (const float*)d_in[13];
  const float* ln2_w    = (const float*)d_in[14];
  const float* ln2_b    = (const float*)d_in[15];
  const float* fc1_w    = (const float*)d_in[16];
  const float* fc1_b    = (const float*)d_in[17];
  const float* fc2_w    = (const float*)d_in[18];
  const float* fc2_b    = (const float*)d_in[19];
  const float* out_w    = (const float*)d_in[20];
  const float* out_b    = (const float*)d_in[21];
  float* outp = (float*)d_out;

  float* xbuf = (float*)d_ws;                                  // 2048*768 f32
  ushort_t* hb16    = (ushort_t*)(xbuf + (size_t)ROWS * E);    // 2048*768
  ushort_t* qkvimg  = hb16 + (size_t)ROWS * E;                 // 2048*2304
  ushort_t* attnw16 = qkvimg + (size_t)ROWS * 3 * E;           // 3528*768
  ushort_t* h1b16   = attnw16 + (size_t)WROWS * E;             // 2048*3072
  ushort_t* wq      = h1b16 + (size_t)ROWS * 4 * E;            // 2304*768
  ushort_t* wp      = wq + (size_t)2304 * 768;                 // 768*768
  ushort_t* w1      = wp + (size_t)768 * 768;                  // 3072*768
  ushort_t* w2      = w1 + (size_t)3072 * 768;                 // 768*3072
  ushort_t* pwT16   = w2 + (size_t)768 * 3072;                 // 768*768
  ushort_t* headW16 = pwT16 + (size_t)768 * 768;               // 256*768
  ushort_t* imb16 = hb16;

  cast_bf16<<<576, 256, 0, stream>>>(patch_w, pwT16, 768 * 768);
  cast_bf16<<<192, 256, 0, stream>>>(out_w, headW16, 256 * 768);

  // ---- patch embed as GEMM (32x64 tiles) ----
  im2col<<<ROWS, 256, 0, stream>>>(x_in, imb16);
  gemm_32<OP_POS, 0><<<768, 128, 0, stream>>>(
      imb16, pwT16, patch_b, nullptr, pos_emb, xbuf, ROWS, E, E, 12);

  int win_i = 0, glob_i = 0;
  for (int i = 0; i < 12; i++) {
    const bool is_win = (WIN_MASK >> i) & 1;

    prep_wt64<<<1728, 256, 0, stream>>>(
        qkv_w + (size_t)i * E * 3 * E, proj_w + (size_t)i * E * E,
        fc1_w + (size_t)i * E * 4 * E, fc2_w + (size_t)i * 4 * E * E,
        wq, wp, w1, w2);

    ln_kernel<<<ROWS / 4, 256, 0, stream>>>(xbuf, ln1_w + i * E, ln1_b + i * E, hb16);

    gemm_bt<OP_QKV, 0><<<36 * 32, 256, 0, stream>>>(
        hb16, wq, qkv_b + i * 3 * E, nullptr, nullptr, qkvimg, ROWS, 3 * E, E, 36);

    if (is_win) {
      attn64<1><<<dim3(4, BW * NH), 256, 0, stream>>>(
          qkvimg, attnw16, rel_h_w + (size_t)win_i * (2 * WS - 1) * HD,
          rel_w_w + (size_t)win_i * (2 * WS - 1) * HD, qkv_b + i * 3 * E, WS, WS);
      win_i++;
      gemm_32<OP_ADD, 2><<<768, 128, 0, stream>>>(
          attnw16, wp, proj_b + i * E, xbuf, nullptr, xbuf, ROWS, E, E, 12);
    } else {
      attn64<0><<<dim3(16, Bsz * NH), 256, 0, stream>>>(
          qkvimg, attnw16, rel_h_g + (size_t)glob_i * (2 * G - 1) * HD,
          rel_w_g + (size_t)glob_i * (2 * G - 1) * HD, qkv_b + i * 3 * E, G, G);
      glob_i++;
      gemm_32<OP_ADD, 0><<<768, 128, 0, stream>>>(
          attnw16, wp, proj_b + i * E, xbuf, nullptr, xbuf, ROWS, E, E, 12);
    }

    ln_kernel<<<ROWS / 4, 256, 0, stream>>>(xbuf, ln2_w + i * E, ln2_b + i * E, hb16);
    gemm_bt<OP_GELU, 0><<<48 * 32, 256, 0, stream>>>(
        hb16, w1, fc1_b + i * 4 * E, nullptr, nullptr, h1b16, ROWS, 4 * E, E, 48);
    gemm_32<OP_ADD, 0><<<768, 128, 0, stream>>>(
        h1b16, w2, fc2_b + i * E, xbuf, nullptr, xbuf, ROWS, E, 4 * E, 12);
  }

  // ---- head (32x64 tiles) ----
  cast_bf16<<<1536, 256, 0, stream>>>(xbuf, hb16, ROWS * E);
  gemm_32<OP_HEAD, 0><<<256, 128, 0, stream>>>(
      hb16, headW16, out_b, nullptr, nullptr, outp, ROWS, 256, E, 4);
}

// Round 17
// 1714.058 us; speedup vs baseline: 1.0890x; 1.0016x over previous
//
#include <hip/hip_runtime.h>
#include <hip/hip_bf16.h>
#include <math.h>

// ---------------- constants ----------------
static constexpr int E   = 768;
static constexpr int NH  = 12;
static constexpr int HD  = 64;
static constexpr int Bsz = 2;
static constexpr int G   = 32;
static constexpr int NTOK = G * G;      // 1024
static constexpr int ROWS = Bsz * NTOK; // 2048
static constexpr int WS  = 14;
static constexpr int NWIN_SIDE = 3;
static constexpr int NWIN = NWIN_SIDE * NWIN_SIDE;
static constexpr int BW  = Bsz * NWIN;   // 18
static constexpr int NW  = WS * WS;      // 196
static constexpr int WROWS = BW * NW;    // 3528
static constexpr int WIN_MASK = 0x6DB;

typedef __attribute__((ext_vector_type(8))) short short8;
typedef __attribute__((ext_vector_type(4))) float f32x4;
typedef unsigned short ushort_t;

__device__ __forceinline__ unsigned short f2bf(float x) {
  union { float f; unsigned u; } v; v.f = x;
  unsigned r = v.u + 0x7fffu + ((v.u >> 16) & 1u);
  return (unsigned short)(r >> 16);
}
__device__ __forceinline__ float bf2f(unsigned short h) {
  union { unsigned u; float f; } v; v.u = ((unsigned)h) << 16;
  return v.f;
}

__device__ __forceinline__ void glds16(const void* g, void* l) {
  __builtin_amdgcn_global_load_lds(
      (const __attribute__((address_space(1))) unsigned*)g,
      (__attribute__((address_space(3))) unsigned*)l, 16, 0, 0);
}

// ---------------- LayerNorm fp32 -> bf16, one wave per row ----------------
__global__ __launch_bounds__(256) void ln_kernel(
    const float* __restrict__ in, const float* __restrict__ w,
    const float* __restrict__ b, ushort_t* __restrict__ out) {
  const int wave = threadIdx.x >> 6, lane = threadIdx.x & 63;
  const int row = blockIdx.x * 4 + wave;
  const float4* r4 = (const float4*)(in + (size_t)row * E);
  float4 v[3];
  v[0] = r4[lane]; v[1] = r4[lane + 64]; v[2] = r4[lane + 128];
  float s = 0.f, s2 = 0.f;
#pragma unroll
  for (int i = 0; i < 3; i++) {
    s += v[i].x + v[i].y + v[i].z + v[i].w;
    s2 += v[i].x * v[i].x + v[i].y * v[i].y + v[i].z * v[i].z + v[i].w * v[i].w;
  }
#pragma unroll
  for (int off = 1; off <= 32; off <<= 1) {
    s += __shfl_xor(s, off);
    s2 += __shfl_xor(s2, off);
  }
  const float mean = s * (1.f / E);
  const float var  = s2 * (1.f / E) - mean * mean;
  const float rs   = rsqrtf(var + 1e-6f);
  ushort_t* o = out + (size_t)row * E;
#pragma unroll
  for (int i = 0; i < 3; i++) {
    const int e0 = (lane + i * 64) * 4;
    ushort4 p;
    p.x = f2bf((v[i].x - mean) * rs * w[e0]     + b[e0]);
    p.y = f2bf((v[i].y - mean) * rs * w[e0 + 1] + b[e0 + 1]);
    p.z = f2bf((v[i].z - mean) * rs * w[e0 + 2] + b[e0 + 2]);
    p.w = f2bf((v[i].w - mean) * rs * w[e0 + 3] + b[e0 + 3]);
    *(ushort4*)&o[e0] = p;
  }
}

enum { OP_QKV = 0, OP_GELU = 1, OP_ADD = 2, OP_POS = 3, OP_HEAD = 4, OP_ADDC = 5 };

// ---------------- bf16 GEMM, 64x64 tile, 4 waves, counted-vmcnt 2-phase ----
template <int OP, int MAP>
__global__ __launch_bounds__(256) void gemm_bt(
    const ushort_t* __restrict__ A, const ushort_t* __restrict__ Bt,
    const float* __restrict__ bias, const float* __restrict__ res,
    const float* __restrict__ pos, void* __restrict__ Cp,
    int M, int N, int K, int ncol) {
  __shared__ ushort_t As[2][64 * 64];
  __shared__ ushort_t Bs[2][64 * 64];
  const int tid = threadIdx.x, wave = tid >> 6, lane = tid & 63;
  const int lx = lane & 15, ly = lane >> 4;

  const int nwg = gridDim.x;
  const int q = nwg >> 3, r = nwg & 7;
  const int xcd = blockIdx.x & 7, loc = blockIdx.x >> 3;
  const int wgid = ((xcd < r) ? xcd * (q + 1) : r * (q + 1) + (xcd - r) * q) + loc;
  const int brow = wgid / ncol, bcol = wgid - brow * ncol;
  const int row0 = brow * 64, col0 = bcol * 64;
  const int wm = (wave >> 1) * 32, wn = (wave & 1) * 32;
  const int rin = lane >> 3, pseg = lane & 7;
  const int lseg = pseg ^ rin;
  f32x4 acc[2][2] = {};

  const ushort_t* aptr[2];
  const ushort_t* bptr[2];
#pragma unroll
  for (int j = 0; j < 2; j++) {
    const int slot = wave * 2 + j;
    int ar = row0 + slot * 8 + rin;
    if (ar >= M) ar = M - 1;
    if (MAP == 2) {
      const int bI = ar >> 10, t = ar & 1023, y = t >> 5, x = t & 31;
      const int by = y / WS, wy = y - by * WS;
      const int bx = x / WS, wx = x - bx * WS;
      const int win = bI * NWIN + by * NWIN_SIDE + bx;
      aptr[j] = &A[((size_t)win * NW + wy * WS + wx) * E + lseg * 8];
    } else {
      aptr[j] = &A[(size_t)ar * K + lseg * 8];
    }
    const int br = col0 + slot * 8 + rin;
    bptr[j] = &Bt[(size_t)br * K + lseg * 8];
  }

#pragma unroll
  for (int j = 0; j < 2; j++) {
    const int slot = wave * 2 + j;
    glds16(aptr[j], &As[0][slot * 512]);
    glds16(bptr[j], &Bs[0][slot * 512]);
  }

  const int nt = K >> 6;
  for (int t = 0; t < nt; t++) {
    const int cur = t & 1;
    if (t + 1 < nt) {
      const int k1 = (t + 1) << 6;
#pragma unroll
      for (int j = 0; j < 2; j++) {
        const int slot = wave * 2 + j;
        glds16(aptr[j] + k1, &As[cur ^ 1][slot * 512]);
        glds16(bptr[j] + k1, &Bs[cur ^ 1][slot * 512]);
      }
      asm volatile("s_waitcnt vmcnt(4)" ::: "memory");
    } else {
      asm volatile("s_waitcnt vmcnt(0)" ::: "memory");
    }
    __builtin_amdgcn_s_barrier();
    __builtin_amdgcn_sched_barrier(0);
#pragma unroll
    for (int kb = 0; kb < 2; kb++) {
      short8 af[2], bfm[2];
#pragma unroll
      for (int m = 0; m < 2; m++) {
        const int rr = wm + m * 16 + lx;
        af[m] = *(const short8*)&As[cur][rr * 64 + (((kb * 4 + ly) ^ (rr & 7)) * 8)];
      }
#pragma unroll
      for (int n = 0; n < 2; n++) {
        const int rr = wn + n * 16 + lx;
        bfm[n] = *(const short8*)&Bs[cur][rr * 64 + (((kb * 4 + ly) ^ (rr & 7)) * 8)];
      }
      __builtin_amdgcn_s_setprio(1);
#pragma unroll
      for (int m = 0; m < 2; m++)
#pragma unroll
        for (int n = 0; n < 2; n++)
          acc[m][n] = __builtin_amdgcn_mfma_f32_16x16x32_bf16(af[m], bfm[n], acc[m][n], 0, 0, 0);
      __builtin_amdgcn_s_setprio(0);
    }
    asm volatile("s_waitcnt lgkmcnt(0)" ::: "memory");
    __builtin_amdgcn_s_barrier();
    __builtin_amdgcn_sched_barrier(0);
  }

#pragma unroll
  for (int m = 0; m < 2; m++) {
#pragma unroll
    for (int r4 = 0; r4 < 4; r4++) {
      const int gr = row0 + wm + m * 16 + ly * 4 + r4;
      if (gr >= M) continue;
#pragma unroll
      for (int n = 0; n < 2; n++) {
        const int gc = col0 + wn + n * 16 + lx;
        float v = acc[m][n][r4] + bias[gc];
        if (OP == OP_GELU) v = 0.5f * v * (1.f + erff(v * 0.70710678118654752f));
        if (OP == OP_ADD || OP == OP_ADDC)  v += res[(size_t)gr * N + gc];
        if (OP == OP_POS)  v += pos[(size_t)(gr & 1023) * N + gc];
        if (OP == OP_QKV || OP == OP_GELU || OP == OP_ADDC)
          ((ushort_t*)Cp)[(size_t)gr * N + gc] = f2bf(v);
        else if (OP == OP_HEAD)
          ((float*)Cp)[(((size_t)(gr >> 10) * 256 + gc) << 10) | (gr & 1023)] = v;
        else
          ((float*)Cp)[(size_t)gr * N + gc] = v;
      }
    }
  }
}

// ---------------- bf16 GEMM, 32x64 tile, 2 waves, for small-N GEMMs --------
template <int OP, int MAP>
__global__ __launch_bounds__(128) void gemm_32(
    const ushort_t* __restrict__ A, const ushort_t* __restrict__ Bt,
    const float* __restrict__ bias, const float* __restrict__ res,
    const float* __restrict__ pos, void* __restrict__ Cp,
    int M, int N, int K, int ncol) {
  __shared__ ushort_t As[2][32 * 64];
  __shared__ ushort_t Bs[2][64 * 64];
  const int tid = threadIdx.x, wave = tid >> 6, lane = tid & 63;
  const int lx = lane & 15, ly = lane >> 4;

  const int nwg = gridDim.x;
  const int q = nwg >> 3, r = nwg & 7;
  const int xcd = blockIdx.x & 7, loc = blockIdx.x >> 3;
  const int wgid = ((xcd < r) ? xcd * (q + 1) : r * (q + 1) + (xcd - r) * q) + loc;
  const int brow = wgid / ncol, bcol = wgid - brow * ncol;
  const int row0 = brow * 32, col0 = bcol * 64;
  const int wn = wave * 32;
  const int rin = lane >> 3, pseg = lane & 7;
  const int lseg = pseg ^ rin;
  f32x4 acc[2][2] = {};

  const ushort_t* aptr[2];
  const ushort_t* bptr[4];
#pragma unroll
  for (int j = 0; j < 2; j++) {
    const int slot = wave * 2 + j;
    int ar = row0 + slot * 8 + rin;
    if (ar >= M) ar = M - 1;
    if (MAP == 2) {
      const int bI = ar >> 10, t = ar & 1023, y = t >> 5, x = t & 31;
      const int by = y / WS, wy = y - by * WS;
      const int bx = x / WS, wx = x - bx * WS;
      const int win = bI * NWIN + by * NWIN_SIDE + bx;
      aptr[j] = &A[((size_t)win * NW + wy * WS + wx) * E + lseg * 8];
    } else {
      aptr[j] = &A[(size_t)ar * K + lseg * 8];
    }
  }
#pragma unroll
  for (int j = 0; j < 4; j++) {
    const int slot = wave * 4 + j;
    const int br = col0 + slot * 8 + rin;
    bptr[j] = &Bt[(size_t)br * K + lseg * 8];
  }

#pragma unroll
  for (int j = 0; j < 2; j++) glds16(aptr[j], &As[0][(wave * 2 + j) * 512]);
#pragma unroll
  for (int j = 0; j < 4; j++) glds16(bptr[j], &Bs[0][(wave * 4 + j) * 512]);

  const int nt = K >> 6;
  for (int t = 0; t < nt; t++) {
    const int cur = t & 1;
    if (t + 1 < nt) {
      const int k1 = (t + 1) << 6;
#pragma unroll
      for (int j = 0; j < 2; j++) glds16(aptr[j] + k1, &As[cur ^ 1][(wave * 2 + j) * 512]);
#pragma unroll
      for (int j = 0; j < 4; j++) glds16(bptr[j] + k1, &Bs[cur ^ 1][(wave * 4 + j) * 512]);
      asm volatile("s_waitcnt vmcnt(6)" ::: "memory");
    } else {
      asm volatile("s_waitcnt vmcnt(0)" ::: "memory");
    }
    __builtin_amdgcn_s_barrier();
    __builtin_amdgcn_sched_barrier(0);
#pragma unroll
    for (int kb = 0; kb < 2; kb++) {
      short8 af[2], bfm[2];
#pragma unroll
      for (int m = 0; m < 2; m++) {
        const int rr = m * 16 + lx;
        af[m] = *(const short8*)&As[cur][rr * 64 + (((kb * 4 + ly) ^ (rr & 7)) * 8)];
      }
#pragma unroll
      for (int n = 0; n < 2; n++) {
        const int rr = wn + n * 16 + lx;
        bfm[n] = *(const short8*)&Bs[cur][rr * 64 + (((kb * 4 + ly) ^ (rr & 7)) * 8)];
      }
      __builtin_amdgcn_s_setprio(1);
#pragma unroll
      for (int m = 0; m < 2; m++)
#pragma unroll
        for (int n = 0; n < 2; n++)
          acc[m][n] = __builtin_amdgcn_mfma_f32_16x16x32_bf16(af[m], bfm[n], acc[m][n], 0, 0, 0);
      __builtin_amdgcn_s_setprio(0);
    }
    asm volatile("s_waitcnt lgkmcnt(0)" ::: "memory");
    __builtin_amdgcn_s_barrier();
    __builtin_amdgcn_sched_barrier(0);
  }

#pragma unroll
  for (int m = 0; m < 2; m++) {
#pragma unroll
    for (int r4 = 0; r4 < 4; r4++) {
      const int gr = row0 + m * 16 + ly * 4 + r4;
      if (gr >= M) continue;
#pragma unroll
      for (int n = 0; n < 2; n++) {
        const int gc = col0 + wn + n * 16 + lx;
        float v = acc[m][n][r4] + bias[gc];
        if (OP == OP_GELU) v = 0.5f * v * (1.f + erff(v * 0.70710678118654752f));
        if (OP == OP_ADD || OP == OP_ADDC)  v += res[(size_t)gr * N + gc];
        if (OP == OP_POS)  v += pos[(size_t)(gr & 1023) * N + gc];
        if (OP == OP_QKV || OP == OP_GELU || OP == OP_ADDC)
          ((ushort_t*)Cp)[(size_t)gr * N + gc] = f2bf(v);
        else if (OP == OP_HEAD)
          ((float*)Cp)[(((size_t)(gr >> 10) * 256 + gc) << 10) | (gr & 1023)] = v;
        else
          ((float*)Cp)[(size_t)gr * N + gc] = v;
      }
    }
  }
}

// ---------------- MFMA flash attention, 4 waves x 64 queries ----------------
template <int WIN>
__global__ __launch_bounds__(256) void attn64(
    const ushort_t* __restrict__ qkv, ushort_t* __restrict__ out,
    const float* __restrict__ relh, const float* __restrict__ relw,
    const float* __restrict__ qkvb, int Hd, int Wd) {
  const int Ntok = Hd * Wd;  // 196 or 1024
  __shared__ ushort_t smem[17664];
  ushort_t* Ks   = smem;           // main [0,2048): 32x64 swizzled
  ushort_t* Vst  = smem + 2048;    // main [2048,4608): [64][40]
  ushort_t* Qs   = smem;           // prologue [0,4096)
  ushort_t* RelS = smem;           // prologue phase 2 [0,4096)
  ushort_t* Ps   = smem + 4608;    // [4][16][40]
  ushort_t* Th   = smem + 7168;    // [64][66]
  ushort_t* Tw   = smem + 11392;   // [64][66]
  ushort_t* khw  = smem + 15616;   // [1024]
  ushort_t* ridx = smem + 16640;   // [1024]

  const int tid = threadIdx.x, wave = tid >> 6, lane = tid & 63;
  const int lx = lane & 15, ly = lane >> 4;
  const int bh = blockIdx.y;
  const int nh = bh % NH, wb = bh / NH;
  int by = 0, bx = 0, b_img;
  if (WIN) {
    b_img = wb / NWIN;
    const int wr = wb - b_img * NWIN;
    by = wr / NWIN_SIDE; bx = wr - by * NWIN_SIDE;
  } else {
    b_img = wb;
  }
  const int q0 = blockIdx.x * 64;
  const size_t base = (size_t)b_img * NTOK * 2304 + nh * 64;

  for (int k = tid; k < 1024; k += 256) {
    const int kc = min(k, Ntok - 1);
    const int kh = kc / Wd, kw = kc - kh * Wd;
    khw[k] = (ushort_t)((kh << 8) | kw);
    if (WIN) {
      const int gy = by * WS + kh, gx = bx * WS + kw;
      ridx[k] = (gy < G && gx < G) ? (ushort_t)(gy * G + gx) : (ushort_t)0xFFFF;
    }
  }
  __syncthreads();

#pragma unroll
  for (int i = 0; i < 2; i++) {
    const int fv = i * 256 + tid;
    const int row = fv >> 3, dv8 = (fv & 7) * 8;
    const int qq = min(q0 + row, Ntok - 1);
    int rI;
    if (WIN) {
      const int t = ridx[qq];
      rI = (t == 0xFFFF) ? 0 : t;
    } else {
      rI = qq;
    }
    short8 v = *(const short8*)&qkv[base + (size_t)rI * 2304 + dv8];
    *(short8*)&Qs[(row * 64 + dv8) ^ ((row & 7) << 3)] = v;
  }
  __syncthreads();

  short8 qa[2];
  {
    const int row = wave * 16 + lx;
#pragma unroll
    for (int kb = 0; kb < 2; kb++)
      qa[kb] = *(const short8*)&Qs[(row * 64 + kb * 32 + ly * 8) ^ ((row & 7) << 3)];
  }
  int qh_r[4], qw_r[4];
#pragma unroll
  for (int r = 0; r < 4; r++) {
    const int qc = min(q0 + wave * 16 + ly * 4 + r, Ntok - 1);
    qh_r[r] = qc / Wd;
    qw_r[r] = qc - qh_r[r] * Wd;
  }
  __syncthreads();

  for (int t = 0; t < 2; t++) {
    const float* rel = t ? relw : relh;
    const int TR = t ? (2 * Wd - 1) : (2 * Hd - 1);
#pragma unroll
    for (int i = 0; i < 2; i++) {
      const int fv = i * 256 + tid;
      const int row = fv >> 3, c8 = (fv & 7) * 8;
      short8 v = {};
      if (row < TR) {
        const float* rp = &rel[(size_t)row * 64 + c8];
        const float4 a = *(const float4*)rp;
        const float4 bq = *(const float4*)(rp + 4);
        v[0] = (short)f2bf(a.x);  v[1] = (short)f2bf(a.y);
        v[2] = (short)f2bf(a.z);  v[3] = (short)f2bf(a.w);
        v[4] = (short)f2bf(bq.x); v[5] = (short)f2bf(bq.y);
        v[6] = (short)f2bf(bq.z); v[7] = (short)f2bf(bq.w);
      }
      *(short8*)&RelS[(row * 64 + c8) ^ ((row & 7) << 3)] = v;
    }
    __syncthreads();
    const int NT = (TR + 15) >> 4;
    ushort_t* T = t ? Tw : Th;
    for (int nt = 0; nt < NT; nt++) {
      f32x4 a = {};
      __builtin_amdgcn_s_setprio(1);
#pragma unroll
      for (int kb = 0; kb < 2; kb++) {
        const int rrow = nt * 16 + lx;
        short8 bfv = *(const short8*)&RelS[(rrow * 64 + kb * 32 + ly * 8) ^ ((rrow & 7) << 3)];
        a = __builtin_amdgcn_mfma_f32_16x16x32_bf16(qa[kb], bfv, a, 0, 0, 0);
      }
      __builtin_amdgcn_s_setprio(0);
#pragma unroll
      for (int reg = 0; reg < 4; reg++)
        T[(wave * 16 + ly * 4 + reg) * 66 + nt * 16 + lx] = f2bf(a[reg]);
    }
    __syncthreads();
  }

  f32x4 o[4] = {};
  float m_[4], l_[4];
#pragma unroll
  for (int r = 0; r < 4; r++) { m_[r] = -3e38f; l_[r] = 0.f; }

  const int nkt = (Ntok + 31) >> 5;
  const int srow = tid >> 3, c7 = tid & 7, dv8s = c7 * 8;
  const int vswz = (c7 & 3) << 3;

  short8 kb8 = {}, vb8 = {};
  if (WIN) {
#pragma unroll
    for (int j = 0; j < 8; j++) {
      kb8[j] = (short)f2bf(qkvb[768 + nh * 64 + dv8s + j]);
      vb8[j] = (short)f2bf(qkvb[1536 + nh * 64 + dv8s + j]);
    }
  }

  auto load_kv = [&](int gk, short8& kv, short8& vv) {
    kv = short8{}; vv = short8{};
    if (gk < Ntok) {
      if (WIN) {
        const int rI = ridx[gk];
        if (rI != 0xFFFF) {
          const size_t a = base + (size_t)rI * 2304;
          kv = *(const short8*)&qkv[a + 768 + dv8s];
          vv = *(const short8*)&qkv[a + 1536 + dv8s];
        } else { kv = kb8; vv = vb8; }
      } else {
        const size_t a = base + (size_t)gk * 2304;
        kv = *(const short8*)&qkv[a + 768 + dv8s];
        vv = *(const short8*)&qkv[a + 1536 + dv8s];
      }
    }
  };

  short8 kpre, vpre;
  load_kv(srow, kpre, vpre);

  for (int kt = 0; kt < nkt; kt++) {
    __syncthreads();
    {
      const int row = srow;
      *(short8*)&Ks[(row * 64 + dv8s) ^ ((row & 7) << 3)] = kpre;
      const int kcol = row ^ vswz;
#pragma unroll
      for (int j = 0; j < 8; j++)
        Vst[(dv8s + j) * 40 + kcol] = (ushort_t)vpre[j];
    }
    if (kt + 1 < nkt) load_kv((kt + 1) * 32 + srow, kpre, vpre);
    __syncthreads();

    f32x4 c[2] = {};
    __builtin_amdgcn_s_setprio(1);
#pragma unroll
    for (int kb = 0; kb < 2; kb++)
#pragma unroll
      for (int ct = 0; ct < 2; ct++) {
        const int krow = ct * 16 + lx;
        short8 kf = *(const short8*)&Ks[(krow * 64 + kb * 32 + ly * 8) ^ ((krow & 7) << 3)];
        c[ct] = __builtin_amdgcn_mfma_f32_16x16x32_bf16(qa[kb], kf, c[ct], 0, 0, 0);
      }
    __builtin_amdgcn_s_setprio(0);

    const int k0a = kt * 32 + lx, k1a = k0a + 16;
    const int tv0 = khw[min(k0a, 1023)], tv1 = khw[min(k1a, 1023)];
    const int kh0 = tv0 >> 8, kw0 = tv0 & 255;
    const int kh1 = tv1 >> 8, kw1 = tv1 & 255;
    float pv0[4], pv1[4], mt[4];
#pragma unroll
    for (int r = 0; r < 4; r++) {
      const int trow = (wave * 16 + ly * 4 + r) * 66;
      float s0 = c[0][r] * 0.125f + bf2f(Th[trow + qh_r[r] - kh0 + Hd - 1])
               + bf2f(Tw[trow + qw_r[r] - kw0 + Wd - 1]);
      float s1 = c[1][r] * 0.125f + bf2f(Th[trow + qh_r[r] - kh1 + Hd - 1])
               + bf2f(Tw[trow + qw_r[r] - kw1 + Wd - 1]);
      if (k0a >= Ntok) s0 = -1e30f;
      if (k1a >= Ntok) s1 = -1e30f;
      pv0[r] = s0; pv1[r] = s1;
      mt[r] = fmaxf(s0, s1);
    }
    const float dmax = fmaxf(fmaxf(mt[0] - m_[0], mt[1] - m_[1]),
                             fmaxf(mt[2] - m_[2], mt[3] - m_[3]));
    if (!__all(dmax <= 8.f)) {
#pragma unroll
      for (int r = 0; r < 4; r++) {
        float mr = mt[r];
#pragma unroll
        for (int off = 1; off <= 8; off <<= 1) mr = fmaxf(mr, __shfl_xor(mr, off));
        const float mn = fmaxf(m_[r], mr);
        const float sc = __expf(m_[r] - mn);
        m_[r] = mn; l_[r] *= sc;
#pragma unroll
        for (int dt = 0; dt < 4; dt++) o[dt][r] *= sc;
      }
    }
#pragma unroll
    for (int r = 0; r < 4; r++) {
      const float p0 = __expf(pv0[r] - m_[r]);
      const float p1 = __expf(pv1[r] - m_[r]);
      l_[r] += p0 + p1;
      const int pb = wave * 640 + (ly * 4 + r) * 40;
      Ps[pb + lx]      = f2bf(p0);
      Ps[pb + 16 + lx] = f2bf(p1);
    }
    short8 pf = *(const short8*)&Ps[wave * 640 + lx * 40 + ly * 8];
    __builtin_amdgcn_s_setprio(1);
#pragma unroll
    for (int dt = 0; dt < 4; dt++) {
      const int drow = dt * 16 + lx;
      short8 vf = *(const short8*)&Vst[drow * 40 + ((ly * 8) ^ (((drow >> 3) & 3) << 3))];
      o[dt] = __builtin_amdgcn_mfma_f32_16x16x32_bf16(pf, vf, o[dt], 0, 0, 0);
    }
    __builtin_amdgcn_s_setprio(0);
  }

#pragma unroll
  for (int r = 0; r < 4; r++) {
#pragma unroll
    for (int off = 1; off <= 8; off <<= 1) l_[r] += __shfl_xor(l_[r], off);
    const int qq = q0 + wave * 16 + ly * 4 + r;
    if (qq >= Ntok) continue;
    const size_t orow = WIN ? ((size_t)wb * NW + qq) : ((size_t)b_img * NTOK + qq);
    const float inv = 1.f / l_[r];
#pragma unroll
    for (int dt = 0; dt < 4; dt++)
      out[orow * E + nh * 64 + dt * 16 + lx] = f2bf(o[dt][r] * inv);
  }
}

// ---------------- im2col ----------------
__global__ __launch_bounds__(256) void im2col(const float* __restrict__ x,
                                              ushort_t* __restrict__ out) {
  const int blk = blockIdx.x;
  const int b = blk >> 10, t = blk & 1023, gy = t >> 5, gx = t & 31;
  for (int k = threadIdx.x; k < 768; k += 256) {
    const int ci = k >> 8, rem = k & 255, py = rem >> 4, px = rem & 15;
    out[(size_t)blk * 768 + k] =
        f2bf(x[(((size_t)b * 3 + ci) * 512 + gy * 16 + py) * 512 + gx * 16 + px]);
  }
}

// ---------------- per-layer weight transpose, 64x64 tiles ----------------
__global__ __launch_bounds__(256) void prep_wt64(
    const float* __restrict__ qkvw, const float* __restrict__ projw,
    const float* __restrict__ fc1w, const float* __restrict__ fc2w,
    ushort_t* __restrict__ wq, ushort_t* __restrict__ wp,
    ushort_t* __restrict__ w1, ushort_t* __restrict__ w2) {
  __shared__ float tile[64][65];
  const int blk = blockIdx.x;
  const float* W; ushort_t* Wt; int Kd, Nd, tn, tk;
  if (blk < 432)       { W = qkvw;  Wt = wq; Kd = 768;  Nd = 2304; tn = blk % 36;          tk = blk / 36; }
  else if (blk < 576)  { W = projw; Wt = wp; Kd = 768;  Nd = 768;  tn = (blk - 432) % 12;  tk = (blk - 432) / 12; }
  else if (blk < 1152) { W = fc1w;  Wt = w1; Kd = 768;  Nd = 3072; tn = (blk - 576) % 48;  tk = (blk - 576) / 48; }
  else                 { W = fc2w;  Wt = w2; Kd = 3072; Nd = 768;  tn = (blk - 1152) % 12; tk = (blk - 1152) / 12; }
  const int k0 = tk * 64, n0 = tn * 64;
  const int kr = threadIdx.x >> 2, cg = (threadIdx.x & 3) * 16;
  const float* src = &W[(size_t)(k0 + kr) * Nd + n0 + cg];
#pragma unroll
  for (int j = 0; j < 4; j++) {
    const float4 v = *(const float4*)&src[j * 4];
    tile[kr][cg + j * 4 + 0] = v.x;
    tile[kr][cg + j * 4 + 1] = v.y;
    tile[kr][cg + j * 4 + 2] = v.z;
    tile[kr][cg + j * 4 + 3] = v.w;
  }
  __syncthreads();
  const int nr = kr;
  short8 o0, o1;
#pragma unroll
  for (int j = 0; j < 8; j++) o0[j] = (short)f2bf(tile[cg + j][nr]);
#pragma unroll
  for (int j = 0; j < 8; j++) o1[j] = (short)f2bf(tile[cg + 8 + j][nr]);
  ushort_t* dst = &Wt[(size_t)(n0 + nr) * Kd + k0 + cg];
  *(short8*)&dst[0] = o0;
  *(short8*)&dst[8] = o1;
}

// ---------------- elementwise fp32 -> bf16 ----------------
__global__ __launch_bounds__(256) void cast_bf16(const float* __restrict__ in,
                                                 ushort_t* __restrict__ out, int n) {
  const int idx = (blockIdx.x * 256 + threadIdx.x) * 4;
  if (idx + 3 < n) {
    const float4 v = *(const float4*)&in[idx];
    ushort4 p;
    p.x = f2bf(v.x); p.y = f2bf(v.y); p.z = f2bf(v.z); p.w = f2bf(v.w);
    *(ushort4*)&out[idx] = p;
  }
}

// ---------------- launch ----------------
extern "C" void kernel_launch(void* const* d_in, const int* in_sizes, int n_in,
                              void* d_out, int out_size, void* d_ws, size_t ws_size,
                              hipStream_t stream) {
  const float* x_in     = (const float*)d_in[0];
  const float* patch_w  = (const float*)d_in[1];
  const float* patch_b  = (const float*)d_in[2];
  const float* pos_emb  = (const float*)d_in[3];
  const float* ln1_w    = (const float*)d_in[4];
  const float* ln1_b    = (const float*)d_in[5];
  const float* qkv_w    = (const float*)d_in[6];
  const float* qkv_b    = (const float*)d_in[7];
  const float* proj_w   = (const float*)d_in[8];
  const float* proj_b   = (const float*)d_in[9];
  const float* rel_h_w  = (const float*)d_in[10];
  const float* rel_w_w  = (const float*)d_in[11];
  const float* rel_h_g  = (const float*)d_in[12];
  const float* rel_w_g  = (const float*)d_in[13];
  const float* ln2_w    = (const float*)d_in[14];
  const float* ln2_b    = (const float*)d_in[15];
  const float* fc1_w    = (const float*)d_in[16];
  const float* fc1_b    = (const float*)d_in[17];
  const float* fc2_w    = (const float*)d_in[18];
  const float* fc2_b    = (const float*)d_in[19];
  const float* out_w    = (const float*)d_in[20];
  const float* out_b    = (const float*)d_in[21];
  float* outp = (float*)d_out;

  float* xbuf = (float*)d_ws;                                  // 2048*768 f32
  ushort_t* hb16    = (ushort_t*)(xbuf + (size_t)ROWS * E);    // 2048*768
  ushort_t* qkvimg  = hb16 + (size_t)ROWS * E;                 // 2048*2304
  ushort_t* attnw16 = qkvimg + (size_t)ROWS * 3 * E;           // 3528*768
  ushort_t* h1b16   = attnw16 + (size_t)WROWS * E;             // 2048*3072
  ushort_t* wq      = h1b16 + (size_t)ROWS * 4 * E;            // 2304*768
  ushort_t* wp      = wq + (size_t)2304 * 768;                 // 768*768
  ushort_t* w1      = wp + (size_t)768 * 768;                  // 3072*768
  ushort_t* w2      = w1 + (size_t)3072 * 768;                 // 768*3072
  ushort_t* pwT16   = w2 + (size_t)768 * 3072;                 // 768*768
  ushort_t* headW16 = pwT16 + (size_t)768 * 768;               // 256*768
  ushort_t* imb16 = hb16;

  cast_bf16<<<576, 256, 0, stream>>>(patch_w, pwT16, 768 * 768);
  cast_bf16<<<192, 256, 0, stream>>>(out_w, headW16, 256 * 768);

  // ---- patch embed as GEMM (32x64 tiles) ----
  im2col<<<ROWS, 256, 0, stream>>>(x_in, imb16);
  gemm_32<OP_POS, 0><<<768, 128, 0, stream>>>(
      imb16, pwT16, patch_b, nullptr, pos_emb, xbuf, ROWS, E, E, 12);

  int win_i = 0, glob_i = 0;
  for (int i = 0; i < 12; i++) {
    const bool is_win = (WIN_MASK >> i) & 1;

    prep_wt64<<<1728, 256, 0, stream>>>(
        qkv_w + (size_t)i * E * 3 * E, proj_w + (size_t)i * E * E,
        fc1_w + (size_t)i * E * 4 * E, fc2_w + (size_t)i * 4 * E * E,
        wq, wp, w1, w2);

    ln_kernel<<<ROWS / 4, 256, 0, stream>>>(xbuf, ln1_w + i * E, ln1_b + i * E, hb16);

    gemm_bt<OP_QKV, 0><<<36 * 32, 256, 0, stream>>>(
        hb16, wq, qkv_b + i * 3 * E, nullptr, nullptr, qkvimg, ROWS, 3 * E, E, 36);

    if (is_win) {
      attn64<1><<<dim3(4, BW * NH), 256, 0, stream>>>(
          qkvimg, attnw16, rel_h_w + (size_t)win_i * (2 * WS - 1) * HD,
          rel_w_w + (size_t)win_i * (2 * WS - 1) * HD, qkv_b + i * 3 * E, WS, WS);
      win_i++;
      gemm_32<OP_ADD, 2><<<768, 128, 0, stream>>>(
          attnw16, wp, proj_b + i * E, xbuf, nullptr, xbuf, ROWS, E, E, 12);
    } else {
      attn64<0><<<dim3(16, Bsz * NH), 256, 0, stream>>>(
          qkvimg, attnw16, rel_h_g + (size_t)glob_i * (2 * G - 1) * HD,
          rel_w_g + (size_t)glob_i * (2 * G - 1) * HD, qkv_b + i * 3 * E, G, G);
      glob_i++;
      gemm_32<OP_ADD, 0><<<768, 128, 0, stream>>>(
          attnw16, wp, proj_b + i * E, xbuf, nullptr, xbuf, ROWS, E, E, 12);
    }

    ln_kernel<<<ROWS / 4, 256, 0, stream>>>(xbuf, ln2_w + i * E, ln2_b + i * E, hb16);
    gemm_bt<OP_GELU, 0><<<48 * 32, 256, 0, stream>>>(
        hb16, w1, fc1_b + i * 4 * E, nullptr, nullptr, h1b16, ROWS, 4 * E, E, 48);
    if (i == 11) {
      // final fc2: fused residual-add + bf16 cast straight into hb16
      // (value-identical to fp32 write + cast_bf16; saves one pass)
      gemm_32<OP_ADDC, 0><<<768, 128, 0, stream>>>(
          h1b16, w2, fc2_b + i * E, xbuf, nullptr, hb16, ROWS, E, 4 * E, 12);
    } else {
      gemm_32<OP_ADD, 0><<<768, 128, 0, stream>>>(
          h1b16, w2, fc2_b + i * E, xbuf, nullptr, xbuf, ROWS, E, 4 * E, 12);
    }
  }

  // ---- head (32x64 tiles) ----
  gemm_32<OP_HEAD, 0><<<256, 128, 0, stream>>>(
      hb16, headW16, out_b, nullptr, nullptr, outp, ROWS, 256, E, 4);
}